// Round 1
// baseline (972.569 us; speedup 1.0000x reference)
//
#include <hip/hip_runtime.h>

// Problem constants
#define EDIM   768
#define E3     2304
#define E9     6912
#define HIDD   150
#define TT     2048
#define SS     96
#define BB     2

// ---------------------------------------------------------------------------
// Kernel 1: attention scores. attn[b,t] = MLP_768->150->150->1(X[b,t,:])
// Block: 256 threads, 8 tokens per block. Grid: B*T/8 = 512.
// Thread map: tok = t>>5 (8 tokens), hg = t&31; lanes hg<30 own 5 h's each.
// ---------------------------------------------------------------------------
__global__ __launch_bounds__(256) void k_attn(
    const float* __restrict__ X,
    const float* __restrict__ aw1, const float* __restrict__ ab1,
    const float* __restrict__ aw2, const float* __restrict__ ab2,
    const float* __restrict__ aw3, const float* __restrict__ ab3,
    float* __restrict__ attn_ws)
{
    __shared__ float xs[8 * EDIM];     // 24 KB
    __shared__ float h1s[8 * 152];
    __shared__ float h2s[8 * 152];
    const int t = threadIdx.x;
    const int base = blockIdx.x * (8 * EDIM);
    for (int idx = t; idx < 8 * EDIM; idx += 256) xs[idx] = X[base + idx];
    __syncthreads();

    const int tok = t >> 5;
    const int hg  = t & 31;
    const int h0  = hg * 5;
    const bool act = (hg < 30);   // h0..h0+4 all < 150

    // layer 1: 768 -> 150, ReLU
    if (act) {
        float acc[5];
        #pragma unroll
        for (int q = 0; q < 5; ++q) acc[q] = ab1[h0 + q];
        for (int k = 0; k < EDIM; ++k) {
            const float x = xs[tok * EDIM + k];
            #pragma unroll
            for (int q = 0; q < 5; ++q) acc[q] += x * aw1[k * HIDD + h0 + q];
        }
        #pragma unroll
        for (int q = 0; q < 5; ++q) h1s[tok * 152 + h0 + q] = fmaxf(acc[q], 0.f);
    }
    __syncthreads();

    // layer 2: 150 -> 150, ReLU
    if (act) {
        float acc[5];
        #pragma unroll
        for (int q = 0; q < 5; ++q) acc[q] = ab2[h0 + q];
        for (int k = 0; k < HIDD; ++k) {
            const float x = h1s[tok * 152 + k];
            #pragma unroll
            for (int q = 0; q < 5; ++q) acc[q] += x * aw2[k * HIDD + h0 + q];
        }
        #pragma unroll
        for (int q = 0; q < 5; ++q) h2s[tok * 152 + h0 + q] = fmaxf(acc[q], 0.f);
    }
    __syncthreads();

    // layer 3: 150 -> 1
    float part = 0.f;
    if (act) {
        #pragma unroll
        for (int q = 0; q < 5; ++q) part += h2s[tok * 152 + h0 + q] * aw3[h0 + q];
    }
    for (int off = 16; off > 0; off >>= 1) part += __shfl_down(part, off, 32);
    if (hg == 0) attn_ws[blockIdx.x * 8 + tok] = part + ab3[0];
}

// ---------------------------------------------------------------------------
// Kernel 2: per-span. Build g_i = [g_start, g_end, g_attn] (write to G_ws),
// compute U[s,h] = g.PA + pb1[h], V[s,h] = g.PB, mention score m[s].
// Block per span: grid = B*S = 192, 256 threads.
// ---------------------------------------------------------------------------
__global__ __launch_bounds__(256) void k_span(
    const float* __restrict__ X, const int* __restrict__ spans,
    const float* __restrict__ mw1, const float* __restrict__ mb1,
    const float* __restrict__ mw2, const float* __restrict__ mb2,
    const float* __restrict__ mw3, const float* __restrict__ mb3,
    const float* __restrict__ pw1, const float* __restrict__ pb1,
    const float* __restrict__ attn_ws,
    float* __restrict__ G_ws, float* __restrict__ U_ws,
    float* __restrict__ V_ws, float* __restrict__ m_ws)
{
    __shared__ float g[E3];        // 9.2 KB
    __shared__ float h1m[152];
    __shared__ float h2m[152];
    __shared__ float red[256];
    const int t  = threadIdx.x;
    const int bs = blockIdx.x;          // b*96 + s
    const int b  = bs / SS;
    const int start = spans[bs];

    const float* xb = X + ((long)b * TT + start) * EDIM;
    const float* ab = attn_ws + b * TT + start;
    float* Gp = G_ws + (long)bs * E3;

    for (int e = t; e < EDIM; e += 256) {
        const float gs = xb[e];
        const float ge = xb[7 * EDIM + e];
        float ga = 0.f;
        #pragma unroll
        for (int w = 0; w < 8; ++w) ga += xb[w * EDIM + e] * ab[w];
        g[e] = gs; g[EDIM + e] = ge; g[2 * EDIM + e] = ga;
        Gp[e] = gs; Gp[EDIM + e] = ge; Gp[2 * EDIM + e] = ga;
    }
    __syncthreads();

    if (t < HIDD) {
        float aU = pb1[t], aV = 0.f, aM = mb1[t];
        for (int k = 0; k < E3; ++k) {
            const float gv = g[k];
            aU += gv * pw1[k * HIDD + t];            // PA rows 0..2303
            aV += gv * pw1[(E3 + k) * HIDD + t];     // PB rows 2304..4607
            aM += gv * mw1[k * HIDD + t];
        }
        U_ws[bs * HIDD + t] = aU;
        V_ws[bs * HIDD + t] = aV;
        h1m[t] = fmaxf(aM, 0.f);
    }
    __syncthreads();
    if (t < HIDD) {
        float a = mb2[t];
        for (int k = 0; k < HIDD; ++k) a += h1m[k] * mw2[k * HIDD + t];
        h2m[t] = fmaxf(a, 0.f);
    }
    __syncthreads();
    red[t] = (t < HIDD) ? h2m[t] * mw3[t] : 0.f;
    __syncthreads();
    for (int off = 128; off > 0; off >>= 1) {
        if (t < off) red[t] += red[t + off];
        __syncthreads();
    }
    if (t == 0) m_ws[bs] = red[0] + mb3[0];
}

// ---------------------------------------------------------------------------
// Kernel 3a: bilinear partials. For block (ks,i,b): accumulate over
// K-range [ks*576, ks*576+576) of  sum_k gi[k]*gj[k]*PC[k,h]  for all
// j in [0,96), h in [0,150). atomicAdd into H1[b,i,j,h].
// 256 threads = 16(tx:j) x 16(ty:h); thread tile 6j x 10h.
// ---------------------------------------------------------------------------
__global__ __launch_bounds__(256) void k_pair1(
    const float* __restrict__ G_ws, const float* __restrict__ pw1,
    float* __restrict__ H1)
{
    __shared__ float gi[576];
    __shared__ float At[32 * 97];    // Gj tile, transposed [kk][j], pad 97
    __shared__ float Bt[32 * 160];   // (gi*PC) tile [kk][h], h padded to 160
    const int t  = threadIdx.x;
    const int ks = blockIdx.x;
    const int i  = blockIdx.y;
    const int b  = blockIdx.z;
    const int k0 = ks * 576;
    const float* Gb = G_ws + (long)b * SS * E3;
    const float* PC = pw1 + 2 * E3 * HIDD;   // rows 4608..6911

    for (int idx = t; idx < 576; idx += 256) gi[idx] = Gb[i * E3 + k0 + idx];

    float acc[6][10];
    #pragma unroll
    for (int jj = 0; jj < 6; ++jj)
        #pragma unroll
        for (int hh = 0; hh < 10; ++hh) acc[jj][hh] = 0.f;

    const int tx = t & 15;   // j group
    const int ty = t >> 4;   // h group
    __syncthreads();

    for (int tt = 0; tt < 18; ++tt) {
        const int kt0 = k0 + tt * 32;
        // stage A: Gj[j][kk] -> At[kk][j]
        for (int idx = t; idx < 3072; idx += 256) {
            const int j = idx >> 5, kk = idx & 31;
            At[kk * 97 + j] = Gb[j * E3 + kt0 + kk];
        }
        // stage B: Bt[kk][h] = gi[k] * PC[k][h]  (h>=150 -> 0)
        {
            const int kk = t >> 3, hseg = t & 7;
            const float gv = gi[tt * 32 + kk];
            const float* pcrow = PC + (kt0 + kk) * HIDD;
            #pragma unroll
            for (int q = 0; q < 20; ++q) {
                const int h = hseg * 20 + q;
                Bt[kk * 160 + h] = (h < HIDD) ? pcrow[h] * gv : 0.f;
            }
        }
        __syncthreads();
        for (int kk = 0; kk < 32; ++kk) {
            float a[6], bb[10];
            #pragma unroll
            for (int jj = 0; jj < 6; ++jj) a[jj] = At[kk * 97 + tx * 6 + jj];
            #pragma unroll
            for (int hh = 0; hh < 10; ++hh) bb[hh] = Bt[kk * 160 + ty * 10 + hh];
            #pragma unroll
            for (int jj = 0; jj < 6; ++jj)
                #pragma unroll
                for (int hh = 0; hh < 10; ++hh) acc[jj][hh] += a[jj] * bb[hh];
        }
        __syncthreads();
    }

    float* Hb = H1 + (long)(b * SS + i) * SS * HIDD;
    #pragma unroll
    for (int jj = 0; jj < 6; ++jj) {
        const int j = tx * 6 + jj;
        #pragma unroll
        for (int hh = 0; hh < 10; ++hh) {
            const int h = ty * 10 + hh;
            if (h < HIDD) atomicAdd(&Hb[j * HIDD + h], acc[jj][hh]);
        }
    }
}

// ---------------------------------------------------------------------------
// Kernel 3b: finish. h1 = H1 + U[i] + V[j] (U already has pb1), ReLU,
// layer2 (pw2,pb2) ReLU, layer3 (pw3,pb3); out = clip((m_i+m_j+sc)/3).
// Block: 8 pairs (j-tile), grid = (12, 96, 2).
// ---------------------------------------------------------------------------
__global__ __launch_bounds__(256) void k_pair2(
    const float* __restrict__ H1,
    const float* __restrict__ U_ws, const float* __restrict__ V_ws,
    const float* __restrict__ m_ws,
    const float* __restrict__ pw2, const float* __restrict__ pb2,
    const float* __restrict__ pw3, const float* __restrict__ pb3,
    float* __restrict__ out)
{
    __shared__ float hp[8 * 152];
    __shared__ float h2p[8 * 152];
    const int t  = threadIdx.x;
    const int jt = blockIdx.x;
    const int i  = blockIdx.y;
    const int b  = blockIdx.z;
    const int bi = b * SS + i;
    const int p  = t >> 5;
    const int hg = t & 31;
    const int h0 = hg * 5;
    const int j  = jt * 8 + p;
    const bool act = (hg < 30);

    if (act) {
        const float* Hrow = H1 + ((long)bi * SS + j) * HIDD;
        const float* Urow = U_ws + bi * HIDD;
        const float* Vrow = V_ws + (b * SS + j) * HIDD;
        #pragma unroll
        for (int q = 0; q < 5; ++q) {
            const int h = h0 + q;
            hp[p * 152 + h] = fmaxf(Hrow[h] + Urow[h] + Vrow[h], 0.f);
        }
    }
    __syncthreads();
    if (act) {
        float a2[5];
        #pragma unroll
        for (int q = 0; q < 5; ++q) a2[q] = pb2[h0 + q];
        for (int k = 0; k < HIDD; ++k) {
            const float x = hp[p * 152 + k];
            #pragma unroll
            for (int q = 0; q < 5; ++q) a2[q] += x * pw2[k * HIDD + h0 + q];
        }
        #pragma unroll
        for (int q = 0; q < 5; ++q) h2p[p * 152 + h0 + q] = fmaxf(a2[q], 0.f);
    }
    __syncthreads();
    float part = 0.f;
    if (act) {
        #pragma unroll
        for (int q = 0; q < 5; ++q) part += h2p[p * 152 + h0 + q] * pw3[h0 + q];
    }
    for (int off = 16; off > 0; off >>= 1) part += __shfl_down(part, off, 32);
    if (hg == 0) {
        const float sc = part + pb3[0];
        const float v = (m_ws[bi] + m_ws[b * SS + j] + sc) * (1.f / 3.f);
        out[(long)bi * SS + j] = fminf(fmaxf(v, 0.f), 1.f);
    }
}

// ---------------------------------------------------------------------------
extern "C" void kernel_launch(void* const* d_in, const int* in_sizes, int n_in,
                              void* d_out, int out_size, void* d_ws, size_t ws_size,
                              hipStream_t stream)
{
    const float* X     = (const float*)d_in[0];
    const int*   spans = (const int*)  d_in[1];
    const float* aw1 = (const float*)d_in[2];
    const float* ab1 = (const float*)d_in[3];
    const float* aw2 = (const float*)d_in[4];
    const float* ab2 = (const float*)d_in[5];
    const float* aw3 = (const float*)d_in[6];
    const float* ab3 = (const float*)d_in[7];
    const float* mw1 = (const float*)d_in[8];
    const float* mb1 = (const float*)d_in[9];
    const float* mw2 = (const float*)d_in[10];
    const float* mb2 = (const float*)d_in[11];
    const float* mw3 = (const float*)d_in[12];
    const float* mb3 = (const float*)d_in[13];
    const float* pw1 = (const float*)d_in[14];
    const float* pb1 = (const float*)d_in[15];
    const float* pw2 = (const float*)d_in[16];
    const float* pb2 = (const float*)d_in[17];
    const float* pw3 = (const float*)d_in[18];
    const float* pb3 = (const float*)d_in[19];
    float* out = (float*)d_out;

    float* ws      = (float*)d_ws;
    float* attn_ws = ws;                       // 4096
    float* G_ws    = attn_ws + BB * TT;        // 2*96*2304 = 442368
    float* U_ws    = G_ws + (long)BB * SS * E3;       // 28800
    float* V_ws    = U_ws + BB * SS * HIDD;           // 28800
    float* m_ws    = V_ws + BB * SS * HIDD;           // 192
    float* H1      = m_ws + BB * SS;                  // 2*96*96*150 = 2764800

    hipMemsetAsync(H1, 0, (size_t)BB * SS * SS * HIDD * sizeof(float), stream);

    k_attn<<<dim3(BB * TT / 8), 256, 0, stream>>>(X, aw1, ab1, aw2, ab2, aw3, ab3, attn_ws);
    k_span<<<dim3(BB * SS), 256, 0, stream>>>(X, spans, mw1, mb1, mw2, mb2, mw3, mb3,
                                              pw1, pb1, attn_ws, G_ws, U_ws, V_ws, m_ws);
    k_pair1<<<dim3(4, SS, BB), 256, 0, stream>>>(G_ws, pw1, H1);
    k_pair2<<<dim3(12, SS, BB), 256, 0, stream>>>(H1, U_ws, V_ws, m_ws,
                                                  pw2, pb2, pw3, pb3, out);
}

// Round 2
// 436.639 us; speedup vs baseline: 2.2274x; 2.2274x over previous
//
#include <hip/hip_runtime.h>

// Problem constants
#define EDIM   768
#define E3     2304
#define HIDD   150
#define TT     2048
#define SS     96
#define BB     2

typedef unsigned short u16;
using frag   = __attribute__((ext_vector_type(8))) short;   // 8 bf16 = 4 VGPR
using f32x4v = __attribute__((ext_vector_type(4))) float;   // 4 fp32 acc

__device__ __forceinline__ u16 bf16rn(float f) {
    union { float f; unsigned u; } v; v.f = f;
    unsigned r = v.u + 0x7FFF + ((v.u >> 16) & 1);
    return (u16)(r >> 16);
}
__device__ __forceinline__ float bf16tof(u16 h) {
    union { unsigned u; float f; } v; v.u = ((unsigned)h) << 16;
    return v.f;
}

// ---------------------------------------------------------------------------
// k_prep: split PC = pw1 rows [2*E3, 3*E3) into bf16 hi/lo, TRANSPOSED:
// PCt_hi[h][k], h in [0,160) (rows 150..159 zero), k in [0,2304).
// Grid: 2304 blocks (one per k), 256 threads (t<160 active).
// ---------------------------------------------------------------------------
__global__ __launch_bounds__(256) void k_prep(
    const float* __restrict__ pw1, u16* __restrict__ PCt_hi, u16* __restrict__ PCt_lo)
{
    const int k = blockIdx.x, t = threadIdx.x;
    if (t < 160) {
        float v = (t < HIDD) ? pw1[(2 * E3 + k) * HIDD + t] : 0.f;
        u16 hi = bf16rn(v);
        u16 lo = bf16rn(v - bf16tof(hi));
        PCt_hi[(long)t * E3 + k] = hi;
        PCt_lo[(long)t * E3 + k] = lo;
    }
}

// ---------------------------------------------------------------------------
// k_attn: attn[b,t] = MLP_768->150->150->1(X[b,t,:]). 8 tokens/block.
// ---------------------------------------------------------------------------
__global__ __launch_bounds__(256) void k_attn(
    const float* __restrict__ X,
    const float* __restrict__ aw1, const float* __restrict__ ab1,
    const float* __restrict__ aw2, const float* __restrict__ ab2,
    const float* __restrict__ aw3, const float* __restrict__ ab3,
    float* __restrict__ attn_ws)
{
    __shared__ float xs[8 * EDIM];
    __shared__ float h1s[8 * 152];
    __shared__ float h2s[8 * 152];
    const int t = threadIdx.x;
    const int base = blockIdx.x * (8 * EDIM);
    for (int idx = t; idx < 8 * EDIM; idx += 256) xs[idx] = X[base + idx];
    __syncthreads();

    const int tok = t >> 5;
    const int hg  = t & 31;
    const int h0  = hg * 5;
    const bool act = (hg < 30);

    if (act) {
        float acc[5];
        #pragma unroll
        for (int q = 0; q < 5; ++q) acc[q] = ab1[h0 + q];
        for (int k = 0; k < EDIM; ++k) {
            const float x = xs[tok * EDIM + k];
            #pragma unroll
            for (int q = 0; q < 5; ++q) acc[q] += x * aw1[k * HIDD + h0 + q];
        }
        #pragma unroll
        for (int q = 0; q < 5; ++q) h1s[tok * 152 + h0 + q] = fmaxf(acc[q], 0.f);
    }
    __syncthreads();

    if (act) {
        float acc[5];
        #pragma unroll
        for (int q = 0; q < 5; ++q) acc[q] = ab2[h0 + q];
        for (int k = 0; k < HIDD; ++k) {
            const float x = h1s[tok * 152 + k];
            #pragma unroll
            for (int q = 0; q < 5; ++q) acc[q] += x * aw2[k * HIDD + h0 + q];
        }
        #pragma unroll
        for (int q = 0; q < 5; ++q) h2s[tok * 152 + h0 + q] = fmaxf(acc[q], 0.f);
    }
    __syncthreads();

    float part = 0.f;
    if (act) {
        #pragma unroll
        for (int q = 0; q < 5; ++q) part += h2s[tok * 152 + h0 + q] * aw3[h0 + q];
    }
    for (int off = 16; off > 0; off >>= 1) part += __shfl_down(part, off, 32);
    if (hg == 0) attn_ws[blockIdx.x * 8 + tok] = part + ab3[0];
}

// ---------------------------------------------------------------------------
// k_span_g: build g_i = [g_start, g_end, g_attn] -> G_ws[b*96+s][2304].
// Grid 192 blocks, 256 threads.
// ---------------------------------------------------------------------------
__global__ __launch_bounds__(256) void k_span_g(
    const float* __restrict__ X, const int* __restrict__ spans,
    const float* __restrict__ attn_ws, float* __restrict__ G_ws)
{
    const int t  = threadIdx.x;
    const int bs = blockIdx.x;
    const int b  = bs / SS;
    const int start = spans[bs];
    const float* xb = X + ((long)b * TT + start) * EDIM;
    const float* ab = attn_ws + b * TT + start;
    float* Gp = G_ws + (long)bs * E3;

    for (int e = t; e < EDIM; e += 256) {
        const float gs = xb[e];
        const float ge = xb[7 * EDIM + e];
        float ga = 0.f;
        #pragma unroll
        for (int w = 0; w < 8; ++w) ga += xb[w * EDIM + e] * ab[w];
        Gp[e] = gs; Gp[EDIM + e] = ge; Gp[2 * EDIM + e] = ga;
    }
}

// ---------------------------------------------------------------------------
// k_span_uvm: partial matvecs over k-third: U += g.PA, V += g.PB, M += g.MW1.
// Grid (3 ks, 192 bs), 192 threads. Atomic fp32 adds into zeroed buffers.
// ---------------------------------------------------------------------------
__global__ __launch_bounds__(192) void k_span_uvm(
    const float* __restrict__ G_ws,
    const float* __restrict__ pw1, const float* __restrict__ mw1,
    float* __restrict__ U_ws, float* __restrict__ V_ws, float* __restrict__ M_ws)
{
    __shared__ float gsh[768];
    const int t  = threadIdx.x;
    const int ks = blockIdx.x;
    const int bs = blockIdx.y;
    const int k0 = ks * 768;
    const float* Gp = G_ws + (long)bs * E3 + k0;
    for (int e = t; e < 768; e += 192) gsh[e] = Gp[e];
    __syncthreads();

    if (t < HIDD) {
        float aU = 0.f, aV = 0.f, aM = 0.f;
        for (int k = 0; k < 768; ++k) {
            const float gv = gsh[k];
            aU += gv * pw1[(k0 + k) * HIDD + t];
            aV += gv * pw1[(E3 + k0 + k) * HIDD + t];
            aM += gv * mw1[(k0 + k) * HIDD + t];
        }
        atomicAdd(&U_ws[bs * HIDD + t], aU);
        atomicAdd(&V_ws[bs * HIDD + t], aV);
        atomicAdd(&M_ws[bs * HIDD + t], aM);
    }
}

// ---------------------------------------------------------------------------
// k_mention: mention MLP layers 2-3 from M partials. Grid 192, 256 thr.
// ---------------------------------------------------------------------------
__global__ __launch_bounds__(256) void k_mention(
    const float* __restrict__ M_ws,
    const float* __restrict__ mb1,
    const float* __restrict__ mw2, const float* __restrict__ mb2,
    const float* __restrict__ mw3, const float* __restrict__ mb3,
    float* __restrict__ m_ws)
{
    __shared__ float h1m[152];
    __shared__ float h2m[152];
    __shared__ float red[256];
    const int t  = threadIdx.x;
    const int bs = blockIdx.x;
    if (t < HIDD) h1m[t] = fmaxf(M_ws[bs * HIDD + t] + mb1[t], 0.f);
    __syncthreads();
    if (t < HIDD) {
        float a = mb2[t];
        for (int k = 0; k < HIDD; ++k) a += h1m[k] * mw2[k * HIDD + t];
        h2m[t] = fmaxf(a, 0.f);
    }
    __syncthreads();
    red[t] = (t < HIDD) ? h2m[t] * mw3[t] : 0.f;
    __syncthreads();
    for (int off = 128; off > 0; off >>= 1) {
        if (t < off) red[t] += red[t + off];
        __syncthreads();
    }
    if (t == 0) m_ws[bs] = red[0] + mb3[0];
}

// ---------------------------------------------------------------------------
// k_pairmm: MFMA bilinear. Block (ks,i,b): C[j=96][h=160] += over k-third of
//   (gi[k]*gj[k]) * PC[k][h], via bf16 hi/lo split (3 MFMAs / tile / kstep).
// 256 thr = 4 waves; wave w: j-half = w&1 (3 j-tiles), h-half = w>>1 (5 h-tiles).
// mfma_f32_16x16x32_bf16: A[m=lane&15][k=quad*8+e], B[k=quad*8+e][n=lane&15],
// D[row=quad*4+r][col=lane&15]  (m89/m91-verified layouts).
// ---------------------------------------------------------------------------
__global__ __launch_bounds__(256) void k_pairmm(
    const float* __restrict__ G_ws,
    const u16* __restrict__ PCt_hi, const u16* __restrict__ PCt_lo,
    float* __restrict__ H1parts)
{
    __shared__ float gis[768];
    __shared__ __align__(16) u16 As_hi[96 * 40];
    __shared__ __align__(16) u16 As_lo[96 * 40];
    __shared__ __align__(16) u16 Bs_hi[160 * 40];
    __shared__ __align__(16) u16 Bs_lo[160 * 40];

    const int t  = threadIdx.x;
    const int ks = blockIdx.x;     // k-split 0..2
    const int i  = blockIdx.y;
    const int b  = blockIdx.z;
    const int ksbase = ks * 768;

    const int lane = t & 63;
    const int m    = lane & 15;
    const int quad = lane >> 4;
    const int w    = t >> 6;
    const int jb   = (w & 1) * 48;
    const int hb   = (w >> 1) * 80;

    // stage gi slice once
    const float* Gi = G_ws + (long)(b * SS + i) * E3 + ksbase;
    for (int e = t; e < 768; e += 256) gis[e] = Gi[e];
    __syncthreads();

    f32x4v acc[3][5];
    #pragma unroll
    for (int jt = 0; jt < 3; ++jt)
        #pragma unroll
        for (int ht = 0; ht < 5; ++ht)
            #pragma unroll
            for (int r = 0; r < 4; ++r) acc[jt][ht][r] = 0.f;

    for (int tt = 0; tt < 24; ++tt) {
        const int kk0 = ksbase + tt * 32;
        // ---- stage A: As[j][kk] = split(gj[k]*gi[k]), 96x32 ----
        #pragma unroll
        for (int it = 0; it < 3; ++it) {
            const int u = t + it * 256;          // < 768 = 96 rows x 8 chunks
            const int j = u >> 3, q = u & 7;
            const float4 gv = *(const float4*)&G_ws[(long)(b * SS + j) * E3 + kk0 + q * 4];
            const int kl = tt * 32 + q * 4;
            const float p0 = gv.x * gis[kl + 0];
            const float p1 = gv.y * gis[kl + 1];
            const float p2 = gv.z * gis[kl + 2];
            const float p3 = gv.w * gis[kl + 3];
            ushort4 hv, lv;
            hv.x = bf16rn(p0); lv.x = bf16rn(p0 - bf16tof(hv.x));
            hv.y = bf16rn(p1); lv.y = bf16rn(p1 - bf16tof(hv.y));
            hv.z = bf16rn(p2); lv.z = bf16rn(p2 - bf16tof(hv.z));
            hv.w = bf16rn(p3); lv.w = bf16rn(p3 - bf16tof(hv.w));
            *(ushort4*)&As_hi[j * 40 + q * 4] = hv;
            *(ushort4*)&As_lo[j * 40 + q * 4] = lv;
        }
        // ---- stage B: copy PCt slice [160][32] hi+lo ----
        #pragma unroll
        for (int it = 0; it < 3; ++it) {
            const int v = t + it * 256;
            if (v < 640) {                        // 160 rows x 4 uint4
                const int h = v >> 2, q = v & 3;
                *(uint4*)&Bs_hi[h * 40 + q * 8] = *(const uint4*)&PCt_hi[(long)h * E3 + kk0 + q * 8];
                *(uint4*)&Bs_lo[h * 40 + q * 8] = *(const uint4*)&PCt_lo[(long)h * E3 + kk0 + q * 8];
            }
        }
        __syncthreads();
        // ---- compute: 15 tiles x 3 MFMAs ----
        frag ah[3], al[3];
        #pragma unroll
        for (int jt = 0; jt < 3; ++jt) {
            ah[jt] = *(const frag*)&As_hi[(jb + jt * 16 + m) * 40 + quad * 8];
            al[jt] = *(const frag*)&As_lo[(jb + jt * 16 + m) * 40 + quad * 8];
        }
        #pragma unroll
        for (int ht = 0; ht < 5; ++ht) {
            const frag bh = *(const frag*)&Bs_hi[(hb + ht * 16 + m) * 40 + quad * 8];
            const frag bl = *(const frag*)&Bs_lo[(hb + ht * 16 + m) * 40 + quad * 8];
            #pragma unroll
            for (int jt = 0; jt < 3; ++jt) {
                acc[jt][ht] = __builtin_amdgcn_mfma_f32_16x16x32_bf16(al[jt], bh, acc[jt][ht], 0, 0, 0);
                acc[jt][ht] = __builtin_amdgcn_mfma_f32_16x16x32_bf16(ah[jt], bl, acc[jt][ht], 0, 0, 0);
                acc[jt][ht] = __builtin_amdgcn_mfma_f32_16x16x32_bf16(ah[jt], bh, acc[jt][ht], 0, 0, 0);
            }
        }
        __syncthreads();
    }

    // epilogue: D[row=quad*4+r][col=lane&15]
    float* dst = H1parts + (long)ks * (BB * SS * SS * HIDD);
    #pragma unroll
    for (int jt = 0; jt < 3; ++jt) {
        #pragma unroll
        for (int ht = 0; ht < 5; ++ht) {
            #pragma unroll
            for (int r = 0; r < 4; ++r) {
                const int j = jb + jt * 16 + quad * 4 + r;
                const int h = hb + ht * 16 + m;
                if (h < HIDD)
                    dst[((long)(b * SS + i) * SS + j) * HIDD + h] = acc[jt][ht][r];
            }
        }
    }
}

// ---------------------------------------------------------------------------
// k_pair2: h1 = relu(sum of 3 H1 parts + U[i] + V[j] + pb1), layer2, layer3,
// combine with mention scores, clip. Grid (12, 96, 2), 256 thr, 8 pairs/block.
// ---------------------------------------------------------------------------
__global__ __launch_bounds__(256) void k_pair2(
    const float* __restrict__ H1a, const float* __restrict__ H1b,
    const float* __restrict__ H1c,
    const float* __restrict__ U_ws, const float* __restrict__ V_ws,
    const float* __restrict__ pb1, const float* __restrict__ m_ws,
    const float* __restrict__ pw2, const float* __restrict__ pb2,
    const float* __restrict__ pw3, const float* __restrict__ pb3,
    float* __restrict__ out)
{
    __shared__ float hp[8 * 152];
    __shared__ float h2p[8 * 152];
    const int t  = threadIdx.x;
    const int jt = blockIdx.x;
    const int i  = blockIdx.y;
    const int b  = blockIdx.z;
    const int bi = b * SS + i;
    const int p  = t >> 5;
    const int hg = t & 31;
    const int h0 = hg * 5;
    const int j  = jt * 8 + p;
    const bool act = (hg < 30);

    if (act) {
        const long idx0 = ((long)bi * SS + j) * HIDD;
        const float* Urow = U_ws + bi * HIDD;
        const float* Vrow = V_ws + (b * SS + j) * HIDD;
        #pragma unroll
        for (int q = 0; q < 5; ++q) {
            const int h = h0 + q;
            const float v = H1a[idx0 + h] + H1b[idx0 + h] + H1c[idx0 + h]
                          + Urow[h] + Vrow[h] + pb1[h];
            hp[p * 152 + h] = fmaxf(v, 0.f);
        }
    }
    __syncthreads();
    if (act) {
        float a2[5];
        #pragma unroll
        for (int q = 0; q < 5; ++q) a2[q] = pb2[h0 + q];
        for (int k = 0; k < HIDD; ++k) {
            const float x = hp[p * 152 + k];
            #pragma unroll
            for (int q = 0; q < 5; ++q) a2[q] += x * pw2[k * HIDD + h0 + q];
        }
        #pragma unroll
        for (int q = 0; q < 5; ++q) h2p[p * 152 + h0 + q] = fmaxf(a2[q], 0.f);
    }
    __syncthreads();
    float part = 0.f;
    if (act) {
        #pragma unroll
        for (int q = 0; q < 5; ++q) part += h2p[p * 152 + h0 + q] * pw3[h0 + q];
    }
    for (int off = 16; off > 0; off >>= 1) part += __shfl_down(part, off, 32);
    if (hg == 0) {
        const float sc = part + pb3[0];
        const float v = (m_ws[bi] + m_ws[b * SS + j] + sc) * (1.f / 3.f);
        out[(long)bi * SS + j] = fminf(fmaxf(v, 0.f), 1.f);
    }
}

// ---------------------------------------------------------------------------
extern "C" void kernel_launch(void* const* d_in, const int* in_sizes, int n_in,
                              void* d_out, int out_size, void* d_ws, size_t ws_size,
                              hipStream_t stream)
{
    const float* X     = (const float*)d_in[0];
    const int*   spans = (const int*)  d_in[1];
    const float* aw1 = (const float*)d_in[2];
    const float* ab1 = (const float*)d_in[3];
    const float* aw2 = (const float*)d_in[4];
    const float* ab2 = (const float*)d_in[5];
    const float* aw3 = (const float*)d_in[6];
    const float* ab3 = (const float*)d_in[7];
    const float* mw1 = (const float*)d_in[8];
    const float* mb1 = (const float*)d_in[9];
    const float* mw2 = (const float*)d_in[10];
    const float* mb2 = (const float*)d_in[11];
    const float* mw3 = (const float*)d_in[12];
    const float* mb3 = (const float*)d_in[13];
    const float* pw1 = (const float*)d_in[14];
    const float* pb1 = (const float*)d_in[15];
    const float* pw2 = (const float*)d_in[16];
    const float* pb2 = (const float*)d_in[17];
    const float* pw3 = (const float*)d_in[18];
    const float* pb3 = (const float*)d_in[19];
    float* out = (float*)d_out;

    float* ws      = (float*)d_ws;
    float* attn_ws = ws;                                   // 4096
    float* G_ws    = attn_ws + BB * TT;                    // 442368
    float* U_ws    = G_ws + (long)BB * SS * E3;            // 28800
    float* V_ws    = U_ws + BB * SS * HIDD;                // 28800
    float* M_ws    = V_ws + BB * SS * HIDD;                // 28800
    float* m_ws    = M_ws + BB * SS * HIDD;                // 256 (pad)
    u16*   PCt_hi  = (u16*)(m_ws + 256);                   // 368640 u16
    u16*   PCt_lo  = PCt_hi + (long)160 * E3;              // 368640 u16
    float* H1parts = (float*)(PCt_lo + (long)160 * E3);    // 3 * 2764800

    // zero the atomic-accumulated U/V/M region (contiguous)
    hipMemsetAsync(U_ws, 0, (size_t)3 * BB * SS * HIDD * sizeof(float), stream);

    k_prep<<<dim3(E3), 256, 0, stream>>>(pw1, PCt_hi, PCt_lo);
    k_attn<<<dim3(BB * TT / 8), 256, 0, stream>>>(X, aw1, ab1, aw2, ab2, aw3, ab3, attn_ws);
    k_span_g<<<dim3(BB * SS), 256, 0, stream>>>(X, spans, attn_ws, G_ws);
    k_span_uvm<<<dim3(3, BB * SS), 192, 0, stream>>>(G_ws, pw1, mw1, U_ws, V_ws, M_ws);
    k_mention<<<dim3(BB * SS), 256, 0, stream>>>(M_ws, mb1, mw2, mb2, mw3, mb3, m_ws);
    k_pairmm<<<dim3(3, SS, BB), 256, 0, stream>>>(G_ws, PCt_hi, PCt_lo, H1parts);
    k_pair2<<<dim3(12, SS, BB), 256, 0, stream>>>(
        H1parts, H1parts + (long)BB * SS * SS * HIDD, H1parts + (long)2 * BB * SS * SS * HIDD,
        U_ws, V_ws, pb1, m_ws, pw2, pb2, pw3, pb3, out);
}

// Round 3
// 356.890 us; speedup vs baseline: 2.7251x; 1.2235x over previous
//
#include <hip/hip_runtime.h>

// Problem constants
#define EDIM   768
#define E3     2304
#define HIDD   150
#define TT     2048
#define SS     96
#define BB     2

typedef unsigned short u16;
using frag   = __attribute__((ext_vector_type(8))) short;   // 8 bf16 = 4 VGPR
using f32x4v = __attribute__((ext_vector_type(4))) float;   // 4 fp32 acc

__device__ __forceinline__ u16 bf16rn(float f) {
    union { float f; unsigned u; } v; v.f = f;
    unsigned r = v.u + 0x7FFF + ((v.u >> 16) & 1);
    return (u16)(r >> 16);
}
__device__ __forceinline__ float bf16tof(u16 h) {
    union { unsigned u; float f; } v; v.u = ((unsigned)h) << 16;
    return v.f;
}
__device__ __forceinline__ void split2(float f, u16& hi, u16& lo) {
    hi = bf16rn(f); lo = bf16rn(f - bf16tof(hi));
}

// ---------------------------------------------------------------------------
// Weight prep kernels: build transposed bf16 hi/lo weight buffers.
// ---------------------------------------------------------------------------
// PCt[h][k], h in [0,160) (>=150 zero), k in [0,2304): PC = pw1 rows [2E3,3E3)
__global__ __launch_bounds__(256) void k_prep_pc(
    const float* __restrict__ pw1, u16* __restrict__ PCt_hi, u16* __restrict__ PCt_lo)
{
    const int k = blockIdx.x, t = threadIdx.x;
    if (t < 160) {
        float v = (t < HIDD) ? pw1[(2 * E3 + k) * HIDD + t] : 0.f;
        u16 hi, lo; split2(v, hi, lo);
        PCt_hi[(long)t * E3 + k] = hi;
        PCt_lo[(long)t * E3 + k] = lo;
    }
}
// AW1t[n][k], n in [0,160), k in [0,768)
__global__ __launch_bounds__(256) void k_prep_aw1(
    const float* __restrict__ aw1, u16* __restrict__ W_hi, u16* __restrict__ W_lo)
{
    const int k = blockIdx.x, t = threadIdx.x;
    if (t < 160) {
        float v = (t < HIDD) ? aw1[k * HIDD + t] : 0.f;
        u16 hi, lo; split2(v, hi, lo);
        W_hi[(long)t * EDIM + k] = hi;
        W_lo[(long)t * EDIM + k] = lo;
    }
}
// AW2t[n][k], n,k in [0,160) (zero-padded past 150)
__global__ __launch_bounds__(256) void k_prep_aw2(
    const float* __restrict__ aw2, u16* __restrict__ W_hi, u16* __restrict__ W_lo)
{
    const int k = blockIdx.x, t = threadIdx.x;
    if (t < 160) {
        float v = (t < HIDD && k < HIDD) ? aw2[k * HIDD + t] : 0.f;
        u16 hi, lo; split2(v, hi, lo);
        W_hi[t * 160 + k] = hi;
        W_lo[t * 160 + k] = lo;
    }
}
// W9t[n][k], n in [0,480): seg0=PA cols, seg1=PB cols, seg2=mw1 cols; k in [0,2304)
__global__ __launch_bounds__(512) void k_prep_w9(
    const float* __restrict__ pw1, const float* __restrict__ mw1,
    u16* __restrict__ W_hi, u16* __restrict__ W_lo)
{
    const int k = blockIdx.x, t = threadIdx.x;
    if (t < 480) {
        const int seg = t / 160, idx = t - seg * 160;
        float v = 0.f;
        if (idx < HIDD) {
            if (seg == 0)      v = pw1[k * HIDD + idx];
            else if (seg == 1) v = pw1[(E3 + k) * HIDD + idx];
            else               v = mw1[k * HIDD + idx];
        }
        u16 hi, lo; split2(v, hi, lo);
        W_hi[(long)t * E3 + k] = hi;
        W_lo[(long)t * E3 + k] = lo;
    }
}

// ---------------------------------------------------------------------------
// k_attn_mfma: attn scores ONLY at span-gathered positions (1536 rows).
// Row r = bs*8+w -> token spans[bs]+w. Layer1: MFMA [32x768]@[768x160] hi/lo.
// Layer2: MFMA [32x160]@[160x160]. Layer3: cross-lane dot. Grid 48 x 256thr.
// Wave w: m-tile = w&1 (16 rows), n-range = (w>>1)*80 (5 n-tiles).
// ---------------------------------------------------------------------------
__global__ __launch_bounds__(256) void k_attn_mfma(
    const float* __restrict__ X, const int* __restrict__ spans,
    const u16* __restrict__ AW1t_hi, const u16* __restrict__ AW1t_lo,
    const u16* __restrict__ AW2t_hi, const u16* __restrict__ AW2t_lo,
    const float* __restrict__ ab1, const float* __restrict__ ab2,
    const float* __restrict__ aw3, const float* __restrict__ ab3,
    float* __restrict__ attn_g)
{
    __shared__ __align__(16) u16 As_hi[32 * 40];
    __shared__ __align__(16) u16 As_lo[32 * 40];
    __shared__ __align__(16) u16 Bs_hi[160 * 40];
    __shared__ __align__(16) u16 Bs_lo[160 * 40];
    __shared__ float h1s[32 * 160];
    __shared__ float red[32];

    const int t    = threadIdx.x;
    const int lane = t & 63;
    const int m    = lane & 15;
    const int quad = lane >> 4;
    const int w    = t >> 6;
    const int mt   = (w & 1) * 16;
    const int nb   = (w >> 1) * 80;

    // fixed A-staging assignment: row rr, chunk q
    const int rr = t >> 3, q = t & 7;
    const int grow = blockIdx.x * 32 + rr;
    const int bs = grow >> 3, sw = grow & 7;
    const int b  = bs / SS;
    const int tok = spans[bs] + sw;
    const float* arow = X + ((long)b * TT + tok) * EDIM;

    f32x4v acc[5];
    #pragma unroll
    for (int ht = 0; ht < 5; ++ht)
        #pragma unroll
        for (int r = 0; r < 4; ++r) acc[ht][r] = 0.f;

    for (int tt = 0; tt < 24; ++tt) {
        const int kk0 = tt * 32;
        // A: gather + split 32x32
        {
            const float4 xv = *(const float4*)&arow[kk0 + q * 4];
            ushort4 hv, lv;
            split2(xv.x, hv.x, lv.x); split2(xv.y, hv.y, lv.y);
            split2(xv.z, hv.z, lv.z); split2(xv.w, hv.w, lv.w);
            *(ushort4*)&As_hi[rr * 40 + q * 4] = hv;
            *(ushort4*)&As_lo[rr * 40 + q * 4] = lv;
        }
        // B: AW1t slice 160x32
        #pragma unroll
        for (int it = 0; it < 3; ++it) {
            const int v = t + it * 256;
            if (v < 640) {
                const int h = v >> 2, qq = v & 3;
                *(uint4*)&Bs_hi[h * 40 + qq * 8] = *(const uint4*)&AW1t_hi[(long)h * EDIM + kk0 + qq * 8];
                *(uint4*)&Bs_lo[h * 40 + qq * 8] = *(const uint4*)&AW1t_lo[(long)h * EDIM + kk0 + qq * 8];
            }
        }
        __syncthreads();
        const frag ah = *(const frag*)&As_hi[(mt + m) * 40 + quad * 8];
        const frag al = *(const frag*)&As_lo[(mt + m) * 40 + quad * 8];
        #pragma unroll
        for (int ht = 0; ht < 5; ++ht) {
            const frag bh = *(const frag*)&Bs_hi[(nb + ht * 16 + m) * 40 + quad * 8];
            const frag bl = *(const frag*)&Bs_lo[(nb + ht * 16 + m) * 40 + quad * 8];
            acc[ht] = __builtin_amdgcn_mfma_f32_16x16x32_bf16(al, bh, acc[ht], 0, 0, 0);
            acc[ht] = __builtin_amdgcn_mfma_f32_16x16x32_bf16(ah, bl, acc[ht], 0, 0, 0);
            acc[ht] = __builtin_amdgcn_mfma_f32_16x16x32_bf16(ah, bh, acc[ht], 0, 0, 0);
        }
        __syncthreads();
    }
    // layer1 epilogue: h1 = relu(acc + ab1), zero-pad cols 150..159
    #pragma unroll
    for (int ht = 0; ht < 5; ++ht) {
        #pragma unroll
        for (int r = 0; r < 4; ++r) {
            const int row = mt + quad * 4 + r;
            const int col = nb + ht * 16 + m;
            const float v = (col < HIDD) ? fmaxf(acc[ht][r] + ab1[col], 0.f) : 0.f;
            h1s[row * 160 + col] = v;
        }
    }
    __syncthreads();

    // layer2 MFMA: [32x160]@[160x160]
    f32x4v acc2[5];
    #pragma unroll
    for (int ht = 0; ht < 5; ++ht)
        #pragma unroll
        for (int r = 0; r < 4; ++r) acc2[ht][r] = 0.f;

    for (int kk = 0; kk < 5; ++kk) {
        {
            const float4 xv = *(const float4*)&h1s[rr * 160 + kk * 32 + q * 4];
            ushort4 hv, lv;
            split2(xv.x, hv.x, lv.x); split2(xv.y, hv.y, lv.y);
            split2(xv.z, hv.z, lv.z); split2(xv.w, hv.w, lv.w);
            *(ushort4*)&As_hi[rr * 40 + q * 4] = hv;
            *(ushort4*)&As_lo[rr * 40 + q * 4] = lv;
        }
        #pragma unroll
        for (int it = 0; it < 3; ++it) {
            const int v = t + it * 256;
            if (v < 640) {
                const int h = v >> 2, qq = v & 3;
                *(uint4*)&Bs_hi[h * 40 + qq * 8] = *(const uint4*)&AW2t_hi[h * 160 + kk * 32 + qq * 8];
                *(uint4*)&Bs_lo[h * 40 + qq * 8] = *(const uint4*)&AW2t_lo[h * 160 + kk * 32 + qq * 8];
            }
        }
        __syncthreads();
        const frag ah = *(const frag*)&As_hi[(mt + m) * 40 + quad * 8];
        const frag al = *(const frag*)&As_lo[(mt + m) * 40 + quad * 8];
        #pragma unroll
        for (int ht = 0; ht < 5; ++ht) {
            const frag bh = *(const frag*)&Bs_hi[(nb + ht * 16 + m) * 40 + quad * 8];
            const frag bl = *(const frag*)&Bs_lo[(nb + ht * 16 + m) * 40 + quad * 8];
            acc2[ht] = __builtin_amdgcn_mfma_f32_16x16x32_bf16(al, bh, acc2[ht], 0, 0, 0);
            acc2[ht] = __builtin_amdgcn_mfma_f32_16x16x32_bf16(ah, bl, acc2[ht], 0, 0, 0);
            acc2[ht] = __builtin_amdgcn_mfma_f32_16x16x32_bf16(ah, bh, acc2[ht], 0, 0, 0);
        }
        __syncthreads();
    }

    // layer3: per-row dot with aw3, reduce across 16 m-lanes + 2 n-half waves
    if (t < 32) red[t] = 0.f;
    __syncthreads();
    float s[4] = {0.f, 0.f, 0.f, 0.f};
    #pragma unroll
    for (int ht = 0; ht < 5; ++ht) {
        const int col = nb + ht * 16 + m;
        if (col < HIDD) {
            const float w3 = aw3[col];
            #pragma unroll
            for (int r = 0; r < 4; ++r)
                s[r] += fmaxf(acc2[ht][r] + ab2[col], 0.f) * w3;
        }
    }
    #pragma unroll
    for (int r = 0; r < 4; ++r) {
        for (int off = 8; off > 0; off >>= 1) s[r] += __shfl_down(s[r], off, 16);
    }
    if (m == 0) {
        #pragma unroll
        for (int r = 0; r < 4; ++r) atomicAdd(&red[mt + quad * 4 + r], s[r]);
    }
    __syncthreads();
    if (t < 32) attn_g[blockIdx.x * 32 + t] = red[t] + ab3[0];
}

// ---------------------------------------------------------------------------
// k_span_g: build g_i fp32 (G_ws) AND bf16 hi/lo split (Gs_hi/lo). 192 blocks.
// ---------------------------------------------------------------------------
__global__ __launch_bounds__(256) void k_span_g(
    const float* __restrict__ X, const int* __restrict__ spans,
    const float* __restrict__ attn_g, float* __restrict__ G_ws,
    u16* __restrict__ Gs_hi, u16* __restrict__ Gs_lo)
{
    __shared__ float a8[8];
    const int t  = threadIdx.x;
    const int bs = blockIdx.x;
    const int b  = bs / SS;
    const int start = spans[bs];
    const float* xb = X + ((long)b * TT + start) * EDIM;
    float* Gp = G_ws + (long)bs * E3;
    u16* Gh = Gs_hi + (long)bs * E3;
    u16* Gl = Gs_lo + (long)bs * E3;
    if (t < 8) a8[t] = attn_g[bs * 8 + t];
    __syncthreads();

    for (int e = t; e < EDIM; e += 256) {
        const float gs = xb[e];
        const float ge = xb[7 * EDIM + e];
        float ga = 0.f;
        #pragma unroll
        for (int w = 0; w < 8; ++w) ga += xb[w * EDIM + e] * a8[w];
        Gp[e] = gs; Gp[EDIM + e] = ge; Gp[2 * EDIM + e] = ga;
        u16 hi, lo;
        split2(gs, hi, lo); Gh[e] = hi;            Gl[e] = lo;
        split2(ge, hi, lo); Gh[EDIM + e] = hi;     Gl[EDIM + e] = lo;
        split2(ga, hi, lo); Gh[2 * EDIM + e] = hi; Gl[2 * EDIM + e] = lo;
    }
}

// ---------------------------------------------------------------------------
// k_uvm: MFMA GEMM [192x2304] @ W9t[480x2304]^T -> UVM[3][192][160].
// Grid (mb=3, nb=3, ks=4), 256 thr. atomicAdd fp32 partials (zeroed before).
// ---------------------------------------------------------------------------
__global__ __launch_bounds__(256) void k_uvm(
    const u16* __restrict__ Gs_hi, const u16* __restrict__ Gs_lo,
    const u16* __restrict__ W9t_hi, const u16* __restrict__ W9t_lo,
    float* __restrict__ UVM)
{
    __shared__ __align__(16) u16 As_hi[64 * 40];
    __shared__ __align__(16) u16 As_lo[64 * 40];
    __shared__ __align__(16) u16 Bs_hi[160 * 40];
    __shared__ __align__(16) u16 Bs_lo[160 * 40];

    const int t    = threadIdx.x;
    const int mb   = blockIdx.x;
    const int nb   = blockIdx.y;
    const int ks   = blockIdx.z;
    const int lane = t & 63;
    const int m    = lane & 15;
    const int quad = lane >> 4;
    const int w    = t >> 6;
    const int mhalf = (w & 1) * 32;
    const int nbase = (w >> 1) * 80;
    const int arr = t >> 2, aq = t & 3;

    f32x4v acc[2][5];
    #pragma unroll
    for (int i = 0; i < 2; ++i)
        #pragma unroll
        for (int j = 0; j < 5; ++j)
            #pragma unroll
            for (int r = 0; r < 4; ++r) acc[i][j][r] = 0.f;

    for (int tt = 0; tt < 18; ++tt) {
        const int kk0 = ks * 576 + tt * 32;
        *(uint4*)&As_hi[arr * 40 + aq * 8] = *(const uint4*)&Gs_hi[(long)(mb * 64 + arr) * E3 + kk0 + aq * 8];
        *(uint4*)&As_lo[arr * 40 + aq * 8] = *(const uint4*)&Gs_lo[(long)(mb * 64 + arr) * E3 + kk0 + aq * 8];
        #pragma unroll
        for (int it = 0; it < 3; ++it) {
            const int v = t + it * 256;
            if (v < 640) {
                const int h = v >> 2, qq = v & 3;
                *(uint4*)&Bs_hi[h * 40 + qq * 8] = *(const uint4*)&W9t_hi[(long)(nb * 160 + h) * E3 + kk0 + qq * 8];
                *(uint4*)&Bs_lo[h * 40 + qq * 8] = *(const uint4*)&W9t_lo[(long)(nb * 160 + h) * E3 + kk0 + qq * 8];
            }
        }
        __syncthreads();
        frag ah[2], al[2];
        #pragma unroll
        for (int mt = 0; mt < 2; ++mt) {
            ah[mt] = *(const frag*)&As_hi[(mhalf + mt * 16 + m) * 40 + quad * 8];
            al[mt] = *(const frag*)&As_lo[(mhalf + mt * 16 + m) * 40 + quad * 8];
        }
        #pragma unroll
        for (int ht = 0; ht < 5; ++ht) {
            const frag bh = *(const frag*)&Bs_hi[(nbase + ht * 16 + m) * 40 + quad * 8];
            const frag bl = *(const frag*)&Bs_lo[(nbase + ht * 16 + m) * 40 + quad * 8];
            #pragma unroll
            for (int mt = 0; mt < 2; ++mt) {
                acc[mt][ht] = __builtin_amdgcn_mfma_f32_16x16x32_bf16(al[mt], bh, acc[mt][ht], 0, 0, 0);
                acc[mt][ht] = __builtin_amdgcn_mfma_f32_16x16x32_bf16(ah[mt], bl, acc[mt][ht], 0, 0, 0);
                acc[mt][ht] = __builtin_amdgcn_mfma_f32_16x16x32_bf16(ah[mt], bh, acc[mt][ht], 0, 0, 0);
            }
        }
        __syncthreads();
    }
    float* dst = UVM + (long)nb * (192 * 160);
    #pragma unroll
    for (int mt = 0; mt < 2; ++mt) {
        #pragma unroll
        for (int ht = 0; ht < 5; ++ht) {
            #pragma unroll
            for (int r = 0; r < 4; ++r) {
                const int row = mb * 64 + mhalf + mt * 16 + quad * 4 + r;
                const int c   = nbase + ht * 16 + m;
                atomicAdd(&dst[row * 160 + c], acc[mt][ht][r]);
            }
        }
    }
}

// ---------------------------------------------------------------------------
// k_mention: mention MLP layers 2-3 from M partials (stride 160). 192 blocks.
// ---------------------------------------------------------------------------
__global__ __launch_bounds__(256) void k_mention(
    const float* __restrict__ M_ws,
    const float* __restrict__ mb1,
    const float* __restrict__ mw2, const float* __restrict__ mb2,
    const float* __restrict__ mw3, const float* __restrict__ mb3,
    float* __restrict__ m_ws)
{
    __shared__ float h1m[152];
    __shared__ float h2m[152];
    __shared__ float red[256];
    const int t  = threadIdx.x;
    const int bs = blockIdx.x;
    if (t < HIDD) h1m[t] = fmaxf(M_ws[bs * 160 + t] + mb1[t], 0.f);
    __syncthreads();
    if (t < HIDD) {
        float a = mb2[t];
        for (int k = 0; k < HIDD; ++k) a += h1m[k] * mw2[k * HIDD + t];
        h2m[t] = fmaxf(a, 0.f);
    }
    __syncthreads();
    red[t] = (t < HIDD) ? h2m[t] * mw3[t] : 0.f;
    __syncthreads();
    for (int off = 128; off > 0; off >>= 1) {
        if (t < off) red[t] += red[t + off];
        __syncthreads();
    }
    if (t == 0) m_ws[bs] = red[0] + mb3[0];
}

// ---------------------------------------------------------------------------
// k_pairmm: MFMA bilinear (unchanged from round 2).
// ---------------------------------------------------------------------------
__global__ __launch_bounds__(256) void k_pairmm(
    const float* __restrict__ G_ws,
    const u16* __restrict__ PCt_hi, const u16* __restrict__ PCt_lo,
    float* __restrict__ H1parts)
{
    __shared__ float gis[768];
    __shared__ __align__(16) u16 As_hi[96 * 40];
    __shared__ __align__(16) u16 As_lo[96 * 40];
    __shared__ __align__(16) u16 Bs_hi[160 * 40];
    __shared__ __align__(16) u16 Bs_lo[160 * 40];

    const int t  = threadIdx.x;
    const int ks = blockIdx.x;
    const int i  = blockIdx.y;
    const int b  = blockIdx.z;
    const int ksbase = ks * 768;

    const int lane = t & 63;
    const int m    = lane & 15;
    const int quad = lane >> 4;
    const int w    = t >> 6;
    const int jb   = (w & 1) * 48;
    const int hb   = (w >> 1) * 80;

    const float* Gi = G_ws + (long)(b * SS + i) * E3 + ksbase;
    for (int e = t; e < 768; e += 256) gis[e] = Gi[e];
    __syncthreads();

    f32x4v acc[3][5];
    #pragma unroll
    for (int jt = 0; jt < 3; ++jt)
        #pragma unroll
        for (int ht = 0; ht < 5; ++ht)
            #pragma unroll
            for (int r = 0; r < 4; ++r) acc[jt][ht][r] = 0.f;

    for (int tt = 0; tt < 24; ++tt) {
        const int kk0 = ksbase + tt * 32;
        #pragma unroll
        for (int it = 0; it < 3; ++it) {
            const int u = t + it * 256;
            const int j = u >> 3, q = u & 7;
            const float4 gv = *(const float4*)&G_ws[(long)(b * SS + j) * E3 + kk0 + q * 4];
            const int kl = tt * 32 + q * 4;
            const float p0 = gv.x * gis[kl + 0];
            const float p1 = gv.y * gis[kl + 1];
            const float p2 = gv.z * gis[kl + 2];
            const float p3 = gv.w * gis[kl + 3];
            ushort4 hv, lv;
            split2(p0, hv.x, lv.x); split2(p1, hv.y, lv.y);
            split2(p2, hv.z, lv.z); split2(p3, hv.w, lv.w);
            *(ushort4*)&As_hi[j * 40 + q * 4] = hv;
            *(ushort4*)&As_lo[j * 40 + q * 4] = lv;
        }
        #pragma unroll
        for (int it = 0; it < 3; ++it) {
            const int v = t + it * 256;
            if (v < 640) {
                const int h = v >> 2, q = v & 3;
                *(uint4*)&Bs_hi[h * 40 + q * 8] = *(const uint4*)&PCt_hi[(long)h * E3 + kk0 + q * 8];
                *(uint4*)&Bs_lo[h * 40 + q * 8] = *(const uint4*)&PCt_lo[(long)h * E3 + kk0 + q * 8];
            }
        }
        __syncthreads();
        frag ah[3], al[3];
        #pragma unroll
        for (int jt = 0; jt < 3; ++jt) {
            ah[jt] = *(const frag*)&As_hi[(jb + jt * 16 + m) * 40 + quad * 8];
            al[jt] = *(const frag*)&As_lo[(jb + jt * 16 + m) * 40 + quad * 8];
        }
        #pragma unroll
        for (int ht = 0; ht < 5; ++ht) {
            const frag bh = *(const frag*)&Bs_hi[(hb + ht * 16 + m) * 40 + quad * 8];
            const frag bl = *(const frag*)&Bs_lo[(hb + ht * 16 + m) * 40 + quad * 8];
            #pragma unroll
            for (int jt = 0; jt < 3; ++jt) {
                acc[jt][ht] = __builtin_amdgcn_mfma_f32_16x16x32_bf16(al[jt], bh, acc[jt][ht], 0, 0, 0);
                acc[jt][ht] = __builtin_amdgcn_mfma_f32_16x16x32_bf16(ah[jt], bl, acc[jt][ht], 0, 0, 0);
                acc[jt][ht] = __builtin_amdgcn_mfma_f32_16x16x32_bf16(ah[jt], bh, acc[jt][ht], 0, 0, 0);
            }
        }
        __syncthreads();
    }

    float* dst = H1parts + (long)ks * (BB * SS * SS * HIDD);
    #pragma unroll
    for (int jt = 0; jt < 3; ++jt) {
        #pragma unroll
        for (int ht = 0; ht < 5; ++ht) {
            #pragma unroll
            for (int r = 0; r < 4; ++r) {
                const int j = jb + jt * 16 + quad * 4 + r;
                const int h = hb + ht * 16 + m;
                if (h < HIDD)
                    dst[((long)(b * SS + i) * SS + j) * HIDD + h] = acc[jt][ht][r];
            }
        }
    }
}

// ---------------------------------------------------------------------------
// k_pair2: finish pairwise MLP (U/V stride now 160). Grid (12,96,2).
// ---------------------------------------------------------------------------
__global__ __launch_bounds__(256) void k_pair2(
    const float* __restrict__ H1a, const float* __restrict__ H1b,
    const float* __restrict__ H1c,
    const float* __restrict__ U_ws, const float* __restrict__ V_ws,
    const float* __restrict__ pb1, const float* __restrict__ m_ws,
    const float* __restrict__ pw2, const float* __restrict__ pb2,
    const float* __restrict__ pw3, const float* __restrict__ pb3,
    float* __restrict__ out)
{
    __shared__ float hp[8 * 152];
    __shared__ float h2p[8 * 152];
    const int t  = threadIdx.x;
    const int jt = blockIdx.x;
    const int i  = blockIdx.y;
    const int b  = blockIdx.z;
    const int bi = b * SS + i;
    const int p  = t >> 5;
    const int hg = t & 31;
    const int h0 = hg * 5;
    const int j  = jt * 8 + p;
    const bool act = (hg < 30);

    if (act) {
        const long idx0 = ((long)bi * SS + j) * HIDD;
        const float* Urow = U_ws + bi * 160;
        const float* Vrow = V_ws + (b * SS + j) * 160;
        #pragma unroll
        for (int q = 0; q < 5; ++q) {
            const int h = h0 + q;
            const float v = H1a[idx0 + h] + H1b[idx0 + h] + H1c[idx0 + h]
                          + Urow[h] + Vrow[h] + pb1[h];
            hp[p * 152 + h] = fmaxf(v, 0.f);
        }
    }
    __syncthreads();
    if (act) {
        float a2[5];
        #pragma unroll
        for (int q = 0; q < 5; ++q) a2[q] = pb2[h0 + q];
        for (int k = 0; k < HIDD; ++k) {
            const float x = hp[p * 152 + k];
            #pragma unroll
            for (int q = 0; q < 5; ++q) a2[q] += x * pw2[k * HIDD + h0 + q];
        }
        #pragma unroll
        for (int q = 0; q < 5; ++q) h2p[p * 152 + h0 + q] = fmaxf(a2[q], 0.f);
    }
    __syncthreads();
    float part = 0.f;
    if (act) {
        #pragma unroll
        for (int q = 0; q < 5; ++q) part += h2p[p * 152 + h0 + q] * pw3[h0 + q];
    }
    for (int off = 16; off > 0; off >>= 1) part += __shfl_down(part, off, 32);
    if (hg == 0) {
        const float sc = part + pb3[0];
        const float v = (m_ws[bi] + m_ws[b * SS + j] + sc) * (1.f / 3.f);
        out[(long)bi * SS + j] = fminf(fmaxf(v, 0.f), 1.f);
    }
}

// ---------------------------------------------------------------------------
extern "C" void kernel_launch(void* const* d_in, const int* in_sizes, int n_in,
                              void* d_out, int out_size, void* d_ws, size_t ws_size,
                              hipStream_t stream)
{
    const float* X     = (const float*)d_in[0];
    const int*   spans = (const int*)  d_in[1];
    const float* aw1 = (const float*)d_in[2];
    const float* ab1 = (const float*)d_in[3];
    const float* aw2 = (const float*)d_in[4];
    const float* ab2 = (const float*)d_in[5];
    const float* aw3 = (const float*)d_in[6];
    const float* ab3 = (const float*)d_in[7];
    const float* mw1 = (const float*)d_in[8];
    const float* mb1 = (const float*)d_in[9];
    const float* mw2 = (const float*)d_in[10];
    const float* mb2 = (const float*)d_in[11];
    const float* mw3 = (const float*)d_in[12];
    const float* mb3 = (const float*)d_in[13];
    const float* pw1 = (const float*)d_in[14];
    const float* pb1 = (const float*)d_in[15];
    const float* pw2 = (const float*)d_in[16];
    const float* pb2 = (const float*)d_in[17];
    const float* pw3 = (const float*)d_in[18];
    const float* pb3 = (const float*)d_in[19];
    float* out = (float*)d_out;

    char* p = (char*)d_ws;
    float* attn_g  = (float*)p;  p += 6144;                       // 1536 f
    float* G_ws    = (float*)p;  p += (long)442368 * 4;           // 192x2304 f
    u16*   Gs_hi   = (u16*)p;    p += (long)442368 * 2;
    u16*   Gs_lo   = (u16*)p;    p += (long)442368 * 2;
    float* UVM     = (float*)p;  p += (long)3 * 192 * 160 * 4;    // U|V|M
    float* m_ws    = (float*)p;  p += 1024;
    u16*   PCt_hi  = (u16*)p;    p += (long)160 * E3 * 2;
    u16*   PCt_lo  = (u16*)p;    p += (long)160 * E3 * 2;
    u16*   AW1t_hi = (u16*)p;    p += (long)160 * EDIM * 2;
    u16*   AW1t_lo = (u16*)p;    p += (long)160 * EDIM * 2;
    u16*   AW2t_hi = (u16*)p;    p += 160 * 160 * 2;
    u16*   AW2t_lo = (u16*)p;    p += 160 * 160 * 2;
    u16*   W9t_hi  = (u16*)p;    p += (long)480 * E3 * 2;
    u16*   W9t_lo  = (u16*)p;    p += (long)480 * E3 * 2;
    float* H1parts = (float*)p;                                   // 3 * 2764800 f

    float* U_ws = UVM;
    float* V_ws = UVM + 192 * 160;
    float* M_ws = UVM + 2 * 192 * 160;

    hipMemsetAsync(UVM, 0, (size_t)3 * 192 * 160 * sizeof(float), stream);

    k_prep_pc <<<dim3(E3),   256, 0, stream>>>(pw1, PCt_hi, PCt_lo);
    k_prep_aw1<<<dim3(EDIM), 256, 0, stream>>>(aw1, AW1t_hi, AW1t_lo);
    k_prep_aw2<<<dim3(160),  256, 0, stream>>>(aw2, AW2t_hi, AW2t_lo);
    k_prep_w9 <<<dim3(E3),   512, 0, stream>>>(pw1, mw1, W9t_hi, W9t_lo);

    k_attn_mfma<<<dim3(48), 256, 0, stream>>>(X, spans, AW1t_hi, AW1t_lo,
                                              AW2t_hi, AW2t_lo, ab1, ab2, aw3, ab3, attn_g);
    k_span_g<<<dim3(BB * SS), 256, 0, stream>>>(X, spans, attn_g, G_ws, Gs_hi, Gs_lo);
    k_uvm<<<dim3(3, 3, 4), 256, 0, stream>>>(Gs_hi, Gs_lo, W9t_hi, W9t_lo, UVM);
    k_mention<<<dim3(BB * SS), 256, 0, stream>>>(M_ws, mb1, mw2, mb2, mw3, mb3, m_ws);
    k_pairmm<<<dim3(3, SS, BB), 256, 0, stream>>>(G_ws, PCt_hi, PCt_lo, H1parts);
    k_pair2<<<dim3(12, SS, BB), 256, 0, stream>>>(
        H1parts, H1parts + (long)BB * SS * SS * HIDD, H1parts + (long)2 * BB * SS * SS * HIDD,
        U_ws, V_ws, pb1, m_ws, pw2, pb2, pw3, pb3, out);
}

// Round 4
// 290.303 us; speedup vs baseline: 3.3502x; 1.2294x over previous
//
#include <hip/hip_runtime.h>

// Problem constants
#define EDIM   768
#define E3     2304
#define HIDD   150
#define TT     2048
#define SS     96
#define BB     2

typedef unsigned short u16;
using frag   = __attribute__((ext_vector_type(8))) short;   // 8 bf16 = 4 VGPR
using f32x4v = __attribute__((ext_vector_type(4))) float;   // 4 fp32 acc

__device__ __forceinline__ u16 bf16rn(float f) {
    union { float f; unsigned u; } v; v.f = f;
    unsigned r = v.u + 0x7FFF + ((v.u >> 16) & 1);
    return (u16)(r >> 16);
}
__device__ __forceinline__ float bf16tof(u16 h) {
    union { unsigned u; float f; } v; v.u = ((unsigned)h) << 16;
    return v.f;
}
__device__ __forceinline__ void split2(float f, u16& hi, u16& lo) {
    hi = bf16rn(f); lo = bf16rn(f - bf16tof(hi));
}

// ---------------------------------------------------------------------------
// Weight prep kernels: build transposed bf16 hi/lo weight buffers.
// ---------------------------------------------------------------------------
// PCt[h][k], h in [0,160) (>=150 zero), k in [0,2304): PC = pw1 rows [2E3,3E3)
__global__ __launch_bounds__(256) void k_prep_pc(
    const float* __restrict__ pw1, u16* __restrict__ PCt_hi, u16* __restrict__ PCt_lo)
{
    const int k = blockIdx.x, t = threadIdx.x;
    if (t < 160) {
        float v = (t < HIDD) ? pw1[(2 * E3 + k) * HIDD + t] : 0.f;
        u16 hi, lo; split2(v, hi, lo);
        PCt_hi[(long)t * E3 + k] = hi;
        PCt_lo[(long)t * E3 + k] = lo;
    }
}
// AW1t[n][k], n in [0,160), k in [0,768)
__global__ __launch_bounds__(256) void k_prep_aw1(
    const float* __restrict__ aw1, u16* __restrict__ W_hi, u16* __restrict__ W_lo)
{
    const int k = blockIdx.x, t = threadIdx.x;
    if (t < 160) {
        float v = (t < HIDD) ? aw1[k * HIDD + t] : 0.f;
        u16 hi, lo; split2(v, hi, lo);
        W_hi[(long)t * EDIM + k] = hi;
        W_lo[(long)t * EDIM + k] = lo;
    }
}
// AW2t[n][k], n,k in [0,160) (zero-padded past 150)
__global__ __launch_bounds__(256) void k_prep_aw2(
    const float* __restrict__ aw2, u16* __restrict__ W_hi, u16* __restrict__ W_lo)
{
    const int k = blockIdx.x, t = threadIdx.x;
    if (t < 160) {
        float v = (t < HIDD && k < HIDD) ? aw2[k * HIDD + t] : 0.f;
        u16 hi, lo; split2(v, hi, lo);
        W_hi[t * 160 + k] = hi;
        W_lo[t * 160 + k] = lo;
    }
}
// PW2t[n][k], n,k in [0,160) (zero-padded past 150): n = layer2 out, k = h
__global__ __launch_bounds__(256) void k_prep_pw2(
    const float* __restrict__ pw2, u16* __restrict__ W_hi, u16* __restrict__ W_lo)
{
    const int k = blockIdx.x, t = threadIdx.x;
    if (t < 160) {
        float v = (t < HIDD && k < HIDD) ? pw2[k * HIDD + t] : 0.f;
        u16 hi, lo; split2(v, hi, lo);
        W_hi[t * 160 + k] = hi;
        W_lo[t * 160 + k] = lo;
    }
}
// W9t[n][k], n in [0,480): seg0=PA cols, seg1=PB cols, seg2=mw1 cols; k in [0,2304)
__global__ __launch_bounds__(512) void k_prep_w9(
    const float* __restrict__ pw1, const float* __restrict__ mw1,
    u16* __restrict__ W_hi, u16* __restrict__ W_lo)
{
    const int k = blockIdx.x, t = threadIdx.x;
    if (t < 480) {
        const int seg = t / 160, idx = t - seg * 160;
        float v = 0.f;
        if (idx < HIDD) {
            if (seg == 0)      v = pw1[k * HIDD + idx];
            else if (seg == 1) v = pw1[(E3 + k) * HIDD + idx];
            else               v = mw1[k * HIDD + idx];
        }
        u16 hi, lo; split2(v, hi, lo);
        W_hi[(long)t * E3 + k] = hi;
        W_lo[(long)t * E3 + k] = lo;
    }
}

// ---------------------------------------------------------------------------
// k_attn_mfma: attn scores ONLY at span-gathered positions (1536 rows).
// ---------------------------------------------------------------------------
__global__ __launch_bounds__(256) void k_attn_mfma(
    const float* __restrict__ X, const int* __restrict__ spans,
    const u16* __restrict__ AW1t_hi, const u16* __restrict__ AW1t_lo,
    const u16* __restrict__ AW2t_hi, const u16* __restrict__ AW2t_lo,
    const float* __restrict__ ab1, const float* __restrict__ ab2,
    const float* __restrict__ aw3, const float* __restrict__ ab3,
    float* __restrict__ attn_g)
{
    __shared__ __align__(16) u16 As_hi[32 * 40];
    __shared__ __align__(16) u16 As_lo[32 * 40];
    __shared__ __align__(16) u16 Bs_hi[160 * 40];
    __shared__ __align__(16) u16 Bs_lo[160 * 40];
    __shared__ float h1s[32 * 160];
    __shared__ float red[32];

    const int t    = threadIdx.x;
    const int lane = t & 63;
    const int m    = lane & 15;
    const int quad = lane >> 4;
    const int w    = t >> 6;
    const int mt   = (w & 1) * 16;
    const int nb   = (w >> 1) * 80;

    const int rr = t >> 3, q = t & 7;
    const int grow = blockIdx.x * 32 + rr;
    const int bs = grow >> 3, sw = grow & 7;
    const int b  = bs / SS;
    const int tok = spans[bs] + sw;
    const float* arow = X + ((long)b * TT + tok) * EDIM;

    f32x4v acc[5];
    #pragma unroll
    for (int ht = 0; ht < 5; ++ht)
        #pragma unroll
        for (int r = 0; r < 4; ++r) acc[ht][r] = 0.f;

    for (int tt = 0; tt < 24; ++tt) {
        const int kk0 = tt * 32;
        {
            const float4 xv = *(const float4*)&arow[kk0 + q * 4];
            ushort4 hv, lv;
            split2(xv.x, hv.x, lv.x); split2(xv.y, hv.y, lv.y);
            split2(xv.z, hv.z, lv.z); split2(xv.w, hv.w, lv.w);
            *(ushort4*)&As_hi[rr * 40 + q * 4] = hv;
            *(ushort4*)&As_lo[rr * 40 + q * 4] = lv;
        }
        #pragma unroll
        for (int it = 0; it < 3; ++it) {
            const int v = t + it * 256;
            if (v < 640) {
                const int h = v >> 2, qq = v & 3;
                *(uint4*)&Bs_hi[h * 40 + qq * 8] = *(const uint4*)&AW1t_hi[(long)h * EDIM + kk0 + qq * 8];
                *(uint4*)&Bs_lo[h * 40 + qq * 8] = *(const uint4*)&AW1t_lo[(long)h * EDIM + kk0 + qq * 8];
            }
        }
        __syncthreads();
        const frag ah = *(const frag*)&As_hi[(mt + m) * 40 + quad * 8];
        const frag al = *(const frag*)&As_lo[(mt + m) * 40 + quad * 8];
        #pragma unroll
        for (int ht = 0; ht < 5; ++ht) {
            const frag bh = *(const frag*)&Bs_hi[(nb + ht * 16 + m) * 40 + quad * 8];
            const frag bl = *(const frag*)&Bs_lo[(nb + ht * 16 + m) * 40 + quad * 8];
            acc[ht] = __builtin_amdgcn_mfma_f32_16x16x32_bf16(al, bh, acc[ht], 0, 0, 0);
            acc[ht] = __builtin_amdgcn_mfma_f32_16x16x32_bf16(ah, bl, acc[ht], 0, 0, 0);
            acc[ht] = __builtin_amdgcn_mfma_f32_16x16x32_bf16(ah, bh, acc[ht], 0, 0, 0);
        }
        __syncthreads();
    }
    #pragma unroll
    for (int ht = 0; ht < 5; ++ht) {
        #pragma unroll
        for (int r = 0; r < 4; ++r) {
            const int row = mt + quad * 4 + r;
            const int col = nb + ht * 16 + m;
            const float v = (col < HIDD) ? fmaxf(acc[ht][r] + ab1[col], 0.f) : 0.f;
            h1s[row * 160 + col] = v;
        }
    }
    __syncthreads();

    f32x4v acc2[5];
    #pragma unroll
    for (int ht = 0; ht < 5; ++ht)
        #pragma unroll
        for (int r = 0; r < 4; ++r) acc2[ht][r] = 0.f;

    for (int kk = 0; kk < 5; ++kk) {
        {
            const float4 xv = *(const float4*)&h1s[rr * 160 + kk * 32 + q * 4];
            ushort4 hv, lv;
            split2(xv.x, hv.x, lv.x); split2(xv.y, hv.y, lv.y);
            split2(xv.z, hv.z, lv.z); split2(xv.w, hv.w, lv.w);
            *(ushort4*)&As_hi[rr * 40 + q * 4] = hv;
            *(ushort4*)&As_lo[rr * 40 + q * 4] = lv;
        }
        #pragma unroll
        for (int it = 0; it < 3; ++it) {
            const int v = t + it * 256;
            if (v < 640) {
                const int h = v >> 2, qq = v & 3;
                *(uint4*)&Bs_hi[h * 40 + qq * 8] = *(const uint4*)&AW2t_hi[h * 160 + kk * 32 + qq * 8];
                *(uint4*)&Bs_lo[h * 40 + qq * 8] = *(const uint4*)&AW2t_lo[h * 160 + kk * 32 + qq * 8];
            }
        }
        __syncthreads();
        const frag ah = *(const frag*)&As_hi[(mt + m) * 40 + quad * 8];
        const frag al = *(const frag*)&As_lo[(mt + m) * 40 + quad * 8];
        #pragma unroll
        for (int ht = 0; ht < 5; ++ht) {
            const frag bh = *(const frag*)&Bs_hi[(nb + ht * 16 + m) * 40 + quad * 8];
            const frag bl = *(const frag*)&Bs_lo[(nb + ht * 16 + m) * 40 + quad * 8];
            acc2[ht] = __builtin_amdgcn_mfma_f32_16x16x32_bf16(al, bh, acc2[ht], 0, 0, 0);
            acc2[ht] = __builtin_amdgcn_mfma_f32_16x16x32_bf16(ah, bl, acc2[ht], 0, 0, 0);
            acc2[ht] = __builtin_amdgcn_mfma_f32_16x16x32_bf16(ah, bh, acc2[ht], 0, 0, 0);
        }
        __syncthreads();
    }

    if (t < 32) red[t] = 0.f;
    __syncthreads();
    float s[4] = {0.f, 0.f, 0.f, 0.f};
    #pragma unroll
    for (int ht = 0; ht < 5; ++ht) {
        const int col = nb + ht * 16 + m;
        if (col < HIDD) {
            const float w3 = aw3[col];
            #pragma unroll
            for (int r = 0; r < 4; ++r)
                s[r] += fmaxf(acc2[ht][r] + ab2[col], 0.f) * w3;
        }
    }
    #pragma unroll
    for (int r = 0; r < 4; ++r) {
        for (int off = 8; off > 0; off >>= 1) s[r] += __shfl_down(s[r], off, 16);
    }
    if (m == 0) {
        #pragma unroll
        for (int r = 0; r < 4; ++r) atomicAdd(&red[mt + quad * 4 + r], s[r]);
    }
    __syncthreads();
    if (t < 32) attn_g[blockIdx.x * 32 + t] = red[t] + ab3[0];
}

// ---------------------------------------------------------------------------
// k_span_g: build g_i fp32 (G_ws) AND bf16 hi/lo split (Gs_hi/lo). 192 blocks.
// ---------------------------------------------------------------------------
__global__ __launch_bounds__(256) void k_span_g(
    const float* __restrict__ X, const int* __restrict__ spans,
    const float* __restrict__ attn_g, float* __restrict__ G_ws,
    u16* __restrict__ Gs_hi, u16* __restrict__ Gs_lo)
{
    __shared__ float a8[8];
    const int t  = threadIdx.x;
    const int bs = blockIdx.x;
    const int b  = bs / SS;
    const int start = spans[bs];
    const float* xb = X + ((long)b * TT + start) * EDIM;
    float* Gp = G_ws + (long)bs * E3;
    u16* Gh = Gs_hi + (long)bs * E3;
    u16* Gl = Gs_lo + (long)bs * E3;
    if (t < 8) a8[t] = attn_g[bs * 8 + t];
    __syncthreads();

    for (int e = t; e < EDIM; e += 256) {
        const float gs = xb[e];
        const float ge = xb[7 * EDIM + e];
        float ga = 0.f;
        #pragma unroll
        for (int w = 0; w < 8; ++w) ga += xb[w * EDIM + e] * a8[w];
        Gp[e] = gs; Gp[EDIM + e] = ge; Gp[2 * EDIM + e] = ga;
        u16 hi, lo;
        split2(gs, hi, lo); Gh[e] = hi;            Gl[e] = lo;
        split2(ge, hi, lo); Gh[EDIM + e] = hi;     Gl[EDIM + e] = lo;
        split2(ga, hi, lo); Gh[2 * EDIM + e] = hi; Gl[2 * EDIM + e] = lo;
    }
}

// ---------------------------------------------------------------------------
// k_uvm: MFMA GEMM [192x2304] @ W9t[480x2304]^T -> UVM[3][192][160].
// ---------------------------------------------------------------------------
__global__ __launch_bounds__(256) void k_uvm(
    const u16* __restrict__ Gs_hi, const u16* __restrict__ Gs_lo,
    const u16* __restrict__ W9t_hi, const u16* __restrict__ W9t_lo,
    float* __restrict__ UVM)
{
    __shared__ __align__(16) u16 As_hi[64 * 40];
    __shared__ __align__(16) u16 As_lo[64 * 40];
    __shared__ __align__(16) u16 Bs_hi[160 * 40];
    __shared__ __align__(16) u16 Bs_lo[160 * 40];

    const int t    = threadIdx.x;
    const int mb   = blockIdx.x;
    const int nb   = blockIdx.y;
    const int ks   = blockIdx.z;
    const int lane = t & 63;
    const int m    = lane & 15;
    const int quad = lane >> 4;
    const int w    = t >> 6;
    const int mhalf = (w & 1) * 32;
    const int nbase = (w >> 1) * 80;
    const int arr = t >> 2, aq = t & 3;

    f32x4v acc[2][5];
    #pragma unroll
    for (int i = 0; i < 2; ++i)
        #pragma unroll
        for (int j = 0; j < 5; ++j)
            #pragma unroll
            for (int r = 0; r < 4; ++r) acc[i][j][r] = 0.f;

    for (int tt = 0; tt < 18; ++tt) {
        const int kk0 = ks * 576 + tt * 32;
        *(uint4*)&As_hi[arr * 40 + aq * 8] = *(const uint4*)&Gs_hi[(long)(mb * 64 + arr) * E3 + kk0 + aq * 8];
        *(uint4*)&As_lo[arr * 40 + aq * 8] = *(const uint4*)&Gs_lo[(long)(mb * 64 + arr) * E3 + kk0 + aq * 8];
        #pragma unroll
        for (int it = 0; it < 3; ++it) {
            const int v = t + it * 256;
            if (v < 640) {
                const int h = v >> 2, qq = v & 3;
                *(uint4*)&Bs_hi[h * 40 + qq * 8] = *(const uint4*)&W9t_hi[(long)(nb * 160 + h) * E3 + kk0 + qq * 8];
                *(uint4*)&Bs_lo[h * 40 + qq * 8] = *(const uint4*)&W9t_lo[(long)(nb * 160 + h) * E3 + kk0 + qq * 8];
            }
        }
        __syncthreads();
        frag ah[2], al[2];
        #pragma unroll
        for (int mt = 0; mt < 2; ++mt) {
            ah[mt] = *(const frag*)&As_hi[(mhalf + mt * 16 + m) * 40 + quad * 8];
            al[mt] = *(const frag*)&As_lo[(mhalf + mt * 16 + m) * 40 + quad * 8];
        }
        #pragma unroll
        for (int ht = 0; ht < 5; ++ht) {
            const frag bh = *(const frag*)&Bs_hi[(nbase + ht * 16 + m) * 40 + quad * 8];
            const frag bl = *(const frag*)&Bs_lo[(nbase + ht * 16 + m) * 40 + quad * 8];
            #pragma unroll
            for (int mt = 0; mt < 2; ++mt) {
                acc[mt][ht] = __builtin_amdgcn_mfma_f32_16x16x32_bf16(al[mt], bh, acc[mt][ht], 0, 0, 0);
                acc[mt][ht] = __builtin_amdgcn_mfma_f32_16x16x32_bf16(ah[mt], bl, acc[mt][ht], 0, 0, 0);
                acc[mt][ht] = __builtin_amdgcn_mfma_f32_16x16x32_bf16(ah[mt], bh, acc[mt][ht], 0, 0, 0);
            }
        }
        __syncthreads();
    }
    float* dst = UVM + (long)nb * (192 * 160);
    #pragma unroll
    for (int mt = 0; mt < 2; ++mt) {
        #pragma unroll
        for (int ht = 0; ht < 5; ++ht) {
            #pragma unroll
            for (int r = 0; r < 4; ++r) {
                const int row = mb * 64 + mhalf + mt * 16 + quad * 4 + r;
                const int c   = nbase + ht * 16 + m;
                atomicAdd(&dst[row * 160 + c], acc[mt][ht][r]);
            }
        }
    }
}

// ---------------------------------------------------------------------------
// k_mention: mention MLP layers 2-3 from M partials (stride 160). 192 blocks.
// ---------------------------------------------------------------------------
__global__ __launch_bounds__(256) void k_mention(
    const float* __restrict__ M_ws,
    const float* __restrict__ mb1,
    const float* __restrict__ mw2, const float* __restrict__ mb2,
    const float* __restrict__ mw3, const float* __restrict__ mb3,
    float* __restrict__ m_ws)
{
    __shared__ float h1m[152];
    __shared__ float h2m[152];
    __shared__ float red[256];
    const int t  = threadIdx.x;
    const int bs = blockIdx.x;
    if (t < HIDD) h1m[t] = fmaxf(M_ws[bs * 160 + t] + mb1[t], 0.f);
    __syncthreads();
    if (t < HIDD) {
        float a = mb2[t];
        for (int k = 0; k < HIDD; ++k) a += h1m[k] * mw2[k * HIDD + t];
        h2m[t] = fmaxf(a, 0.f);
    }
    __syncthreads();
    red[t] = (t < HIDD) ? h2m[t] * mw3[t] : 0.f;
    __syncthreads();
    for (int off = 128; off > 0; off >>= 1) {
        if (t < off) red[t] += red[t + off];
        __syncthreads();
    }
    if (t == 0) m_ws[bs] = red[0] + mb3[0];
}

// ---------------------------------------------------------------------------
// k_pairmm: MFMA bilinear. Output stride now 160 (full cols, aligned rows).
// ---------------------------------------------------------------------------
__global__ __launch_bounds__(256) void k_pairmm(
    const float* __restrict__ G_ws,
    const u16* __restrict__ PCt_hi, const u16* __restrict__ PCt_lo,
    float* __restrict__ H1parts)
{
    __shared__ float gis[768];
    __shared__ __align__(16) u16 As_hi[96 * 40];
    __shared__ __align__(16) u16 As_lo[96 * 40];
    __shared__ __align__(16) u16 Bs_hi[160 * 40];
    __shared__ __align__(16) u16 Bs_lo[160 * 40];

    const int t  = threadIdx.x;
    const int ks = blockIdx.x;
    const int i  = blockIdx.y;
    const int b  = blockIdx.z;
    const int ksbase = ks * 768;

    const int lane = t & 63;
    const int m    = lane & 15;
    const int quad = lane >> 4;
    const int w    = t >> 6;
    const int jb   = (w & 1) * 48;
    const int hb   = (w >> 1) * 80;

    const float* Gi = G_ws + (long)(b * SS + i) * E3 + ksbase;
    for (int e = t; e < 768; e += 256) gis[e] = Gi[e];
    __syncthreads();

    f32x4v acc[3][5];
    #pragma unroll
    for (int jt = 0; jt < 3; ++jt)
        #pragma unroll
        for (int ht = 0; ht < 5; ++ht)
            #pragma unroll
            for (int r = 0; r < 4; ++r) acc[jt][ht][r] = 0.f;

    for (int tt = 0; tt < 24; ++tt) {
        const int kk0 = ksbase + tt * 32;
        #pragma unroll
        for (int it = 0; it < 3; ++it) {
            const int u = t + it * 256;
            const int j = u >> 3, q = u & 7;
            const float4 gv = *(const float4*)&G_ws[(long)(b * SS + j) * E3 + kk0 + q * 4];
            const int kl = tt * 32 + q * 4;
            const float p0 = gv.x * gis[kl + 0];
            const float p1 = gv.y * gis[kl + 1];
            const float p2 = gv.z * gis[kl + 2];
            const float p3 = gv.w * gis[kl + 3];
            ushort4 hv, lv;
            split2(p0, hv.x, lv.x); split2(p1, hv.y, lv.y);
            split2(p2, hv.z, lv.z); split2(p3, hv.w, lv.w);
            *(ushort4*)&As_hi[j * 40 + q * 4] = hv;
            *(ushort4*)&As_lo[j * 40 + q * 4] = lv;
        }
        #pragma unroll
        for (int it = 0; it < 3; ++it) {
            const int v = t + it * 256;
            if (v < 640) {
                const int h = v >> 2, q = v & 3;
                *(uint4*)&Bs_hi[h * 40 + q * 8] = *(const uint4*)&PCt_hi[(long)h * E3 + kk0 + q * 8];
                *(uint4*)&Bs_lo[h * 40 + q * 8] = *(const uint4*)&PCt_lo[(long)h * E3 + kk0 + q * 8];
            }
        }
        __syncthreads();
        frag ah[3], al[3];
        #pragma unroll
        for (int jt = 0; jt < 3; ++jt) {
            ah[jt] = *(const frag*)&As_hi[(jb + jt * 16 + m) * 40 + quad * 8];
            al[jt] = *(const frag*)&As_lo[(jb + jt * 16 + m) * 40 + quad * 8];
        }
        #pragma unroll
        for (int ht = 0; ht < 5; ++ht) {
            const frag bh = *(const frag*)&Bs_hi[(hb + ht * 16 + m) * 40 + quad * 8];
            const frag bl = *(const frag*)&Bs_lo[(hb + ht * 16 + m) * 40 + quad * 8];
            #pragma unroll
            for (int jt = 0; jt < 3; ++jt) {
                acc[jt][ht] = __builtin_amdgcn_mfma_f32_16x16x32_bf16(al[jt], bh, acc[jt][ht], 0, 0, 0);
                acc[jt][ht] = __builtin_amdgcn_mfma_f32_16x16x32_bf16(ah[jt], bl, acc[jt][ht], 0, 0, 0);
                acc[jt][ht] = __builtin_amdgcn_mfma_f32_16x16x32_bf16(ah[jt], bh, acc[jt][ht], 0, 0, 0);
            }
        }
        __syncthreads();
    }

    float* dst = H1parts + (long)ks * ((long)BB * SS * SS * 160);
    #pragma unroll
    for (int jt = 0; jt < 3; ++jt) {
        #pragma unroll
        for (int ht = 0; ht < 5; ++ht) {
            #pragma unroll
            for (int r = 0; r < 4; ++r) {
                const int j = jb + jt * 16 + quad * 4 + r;
                const int h = hb + ht * 16 + m;
                dst[((long)(b * SS + i) * SS + j) * 160 + h] = acc[jt][ht][r];
            }
        }
    }
}

// ---------------------------------------------------------------------------
// k_pair2: MFMA finish. Per (b,i) block: h1[96j x 160h] = relu(sum parts +
// U + V + pb1) -> bf16 hi/lo LDS -> layer2 MFMA vs PW2t -> layer3 dot ->
// combine mention scores, clip. Grid 192, 256 thr.
// ---------------------------------------------------------------------------
__global__ __launch_bounds__(256) void k_pair2(
    const float* __restrict__ H1a, const float* __restrict__ H1b,
    const float* __restrict__ H1c,
    const float* __restrict__ U_ws, const float* __restrict__ V_ws,
    const float* __restrict__ pb1, const float* __restrict__ m_ws,
    const u16* __restrict__ PW2t_hi, const u16* __restrict__ PW2t_lo,
    const float* __restrict__ pb2, const float* __restrict__ pw3,
    const float* __restrict__ pb3,
    float* __restrict__ out)
{
    __shared__ __align__(16) u16 As_hi[96 * 168];
    __shared__ __align__(16) u16 As_lo[96 * 168];
    __shared__ __align__(16) u16 Bs_hi[160 * 40];
    __shared__ __align__(16) u16 Bs_lo[160 * 40];
    __shared__ float uv[160];
    __shared__ float red[96];

    const int t  = threadIdx.x;
    const int bi = blockIdx.x;          // b*96 + i
    const int b  = bi / SS;

    if (t < 160) uv[t] = U_ws[bi * 160 + t] + ((t < HIDD) ? pb1[t] : 0.f);
    if (t < 96) red[t] = 0.f;
    __syncthreads();

    // phase 1: build split h1 in LDS
    const long base = (long)bi * SS * 160;
    for (int u = t; u < 96 * 40; u += 256) {
        const int j = u / 40, hq = u - (u / 40) * 40;
        const int h0 = hq * 4;
        const long idx = base + j * 160 + h0;
        const float4 a  = *(const float4*)&H1a[idx];
        const float4 bb = *(const float4*)&H1b[idx];
        const float4 c  = *(const float4*)&H1c[idx];
        const float4 vv = *(const float4*)&V_ws[(b * SS + j) * 160 + h0];
        const float p0 = fmaxf(a.x + bb.x + c.x + vv.x + uv[h0 + 0], 0.f);
        const float p1 = fmaxf(a.y + bb.y + c.y + vv.y + uv[h0 + 1], 0.f);
        const float p2 = fmaxf(a.z + bb.z + c.z + vv.z + uv[h0 + 2], 0.f);
        const float p3 = fmaxf(a.w + bb.w + c.w + vv.w + uv[h0 + 3], 0.f);
        ushort4 hv, lv;
        split2(p0, hv.x, lv.x); split2(p1, hv.y, lv.y);
        split2(p2, hv.z, lv.z); split2(p3, hv.w, lv.w);
        *(ushort4*)&As_hi[j * 168 + h0] = hv;
        *(ushort4*)&As_lo[j * 168 + h0] = lv;
    }
    __syncthreads();

    // phase 2: layer2 MFMA [96x160]@[160x160]
    const int lane = t & 63;
    const int m    = lane & 15;
    const int quad = lane >> 4;
    const int w    = t >> 6;
    const int jbs  = (w & 1) * 48;     // 3 j-tiles
    const int nbs  = (w >> 1) * 80;    // 5 n-tiles

    f32x4v acc[3][5];
    #pragma unroll
    for (int jt = 0; jt < 3; ++jt)
        #pragma unroll
        for (int ht = 0; ht < 5; ++ht)
            #pragma unroll
            for (int r = 0; r < 4; ++r) acc[jt][ht][r] = 0.f;

    for (int kk = 0; kk < 5; ++kk) {
        #pragma unroll
        for (int it = 0; it < 3; ++it) {
            const int v = t + it * 256;
            if (v < 640) {
                const int n = v >> 2, qq = v & 3;
                *(uint4*)&Bs_hi[n * 40 + qq * 8] = *(const uint4*)&PW2t_hi[n * 160 + kk * 32 + qq * 8];
                *(uint4*)&Bs_lo[n * 40 + qq * 8] = *(const uint4*)&PW2t_lo[n * 160 + kk * 32 + qq * 8];
            }
        }
        __syncthreads();
        frag ah[3], al[3];
        #pragma unroll
        for (int jt = 0; jt < 3; ++jt) {
            ah[jt] = *(const frag*)&As_hi[(jbs + jt * 16 + m) * 168 + kk * 32 + quad * 8];
            al[jt] = *(const frag*)&As_lo[(jbs + jt * 16 + m) * 168 + kk * 32 + quad * 8];
        }
        #pragma unroll
        for (int ht = 0; ht < 5; ++ht) {
            const frag bh = *(const frag*)&Bs_hi[(nbs + ht * 16 + m) * 40 + quad * 8];
            const frag bl = *(const frag*)&Bs_lo[(nbs + ht * 16 + m) * 40 + quad * 8];
            #pragma unroll
            for (int jt = 0; jt < 3; ++jt) {
                acc[jt][ht] = __builtin_amdgcn_mfma_f32_16x16x32_bf16(al[jt], bh, acc[jt][ht], 0, 0, 0);
                acc[jt][ht] = __builtin_amdgcn_mfma_f32_16x16x32_bf16(ah[jt], bl, acc[jt][ht], 0, 0, 0);
                acc[jt][ht] = __builtin_amdgcn_mfma_f32_16x16x32_bf16(ah[jt], bh, acc[jt][ht], 0, 0, 0);
            }
        }
        __syncthreads();
    }

    // phase 3: layer3 dot + reduce
    float s[3][4];
    #pragma unroll
    for (int jt = 0; jt < 3; ++jt)
        #pragma unroll
        for (int r = 0; r < 4; ++r) s[jt][r] = 0.f;
    #pragma unroll
    for (int ht = 0; ht < 5; ++ht) {
        const int col = nbs + ht * 16 + m;
        if (col < HIDD) {
            const float w3 = pw3[col];
            const float b2 = pb2[col];
            #pragma unroll
            for (int jt = 0; jt < 3; ++jt)
                #pragma unroll
                for (int r = 0; r < 4; ++r)
                    s[jt][r] += fmaxf(acc[jt][ht][r] + b2, 0.f) * w3;
        }
    }
    #pragma unroll
    for (int jt = 0; jt < 3; ++jt)
        #pragma unroll
        for (int r = 0; r < 4; ++r)
            for (int off = 8; off > 0; off >>= 1)
                s[jt][r] += __shfl_down(s[jt][r], off, 16);
    if (m == 0) {
        #pragma unroll
        for (int jt = 0; jt < 3; ++jt)
            #pragma unroll
            for (int r = 0; r < 4; ++r)
                atomicAdd(&red[jbs + jt * 16 + quad * 4 + r], s[jt][r]);
    }
    __syncthreads();

    if (t < 96) {
        const float sc = red[t] + pb3[0];
        const float v = (m_ws[bi] + m_ws[b * SS + t] + sc) * (1.f / 3.f);
        out[(long)bi * SS + t] = fminf(fmaxf(v, 0.f), 1.f);
    }
}

// ---------------------------------------------------------------------------
extern "C" void kernel_launch(void* const* d_in, const int* in_sizes, int n_in,
                              void* d_out, int out_size, void* d_ws, size_t ws_size,
                              hipStream_t stream)
{
    const float* X     = (const float*)d_in[0];
    const int*   spans = (const int*)  d_in[1];
    const float* aw1 = (const float*)d_in[2];
    const float* ab1 = (const float*)d_in[3];
    const float* aw2 = (const float*)d_in[4];
    const float* ab2 = (const float*)d_in[5];
    const float* aw3 = (const float*)d_in[6];
    const float* ab3 = (const float*)d_in[7];
    const float* mw1 = (const float*)d_in[8];
    const float* mb1 = (const float*)d_in[9];
    const float* mw2 = (const float*)d_in[10];
    const float* mb2 = (const float*)d_in[11];
    const float* mw3 = (const float*)d_in[12];
    const float* mb3 = (const float*)d_in[13];
    const float* pw1 = (const float*)d_in[14];
    const float* pb1 = (const float*)d_in[15];
    const float* pw2 = (const float*)d_in[16];
    const float* pb2 = (const float*)d_in[17];
    const float* pw3 = (const float*)d_in[18];
    const float* pb3 = (const float*)d_in[19];
    float* out = (float*)d_out;

    char* p = (char*)d_ws;
    float* attn_g  = (float*)p;  p += 6144;                       // 1536 f
    float* G_ws    = (float*)p;  p += (long)442368 * 4;           // 192x2304 f
    u16*   Gs_hi   = (u16*)p;    p += (long)442368 * 2;
    u16*   Gs_lo   = (u16*)p;    p += (long)442368 * 2;
    float* UVM     = (float*)p;  p += (long)3 * 192 * 160 * 4;    // U|V|M
    float* m_ws    = (float*)p;  p += 1024;
    u16*   PCt_hi  = (u16*)p;    p += (long)160 * E3 * 2;
    u16*   PCt_lo  = (u16*)p;    p += (long)160 * E3 * 2;
    u16*   AW1t_hi = (u16*)p;    p += (long)160 * EDIM * 2;
    u16*   AW1t_lo = (u16*)p;    p += (long)160 * EDIM * 2;
    u16*   AW2t_hi = (u16*)p;    p += 160 * 160 * 2;
    u16*   AW2t_lo = (u16*)p;    p += 160 * 160 * 2;
    u16*   PW2t_hi = (u16*)p;    p += 160 * 160 * 2;
    u16*   PW2t_lo = (u16*)p;    p += 160 * 160 * 2;
    u16*   W9t_hi  = (u16*)p;    p += (long)480 * E3 * 2;
    u16*   W9t_lo  = (u16*)p;    p += (long)480 * E3 * 2;
    float* H1parts = (float*)p;   // 3 * 192*96*160 f = 35.4 MB

    float* U_ws = UVM;
    float* V_ws = UVM + 192 * 160;
    float* M_ws = UVM + 2 * 192 * 160;

    hipMemsetAsync(UVM, 0, (size_t)3 * 192 * 160 * sizeof(float), stream);

    k_prep_pc <<<dim3(E3),   256, 0, stream>>>(pw1, PCt_hi, PCt_lo);
    k_prep_aw1<<<dim3(EDIM), 256, 0, stream>>>(aw1, AW1t_hi, AW1t_lo);
    k_prep_aw2<<<dim3(160),  256, 0, stream>>>(aw2, AW2t_hi, AW2t_lo);
    k_prep_pw2<<<dim3(160),  256, 0, stream>>>(pw2, PW2t_hi, PW2t_lo);
    k_prep_w9 <<<dim3(E3),   512, 0, stream>>>(pw1, mw1, W9t_hi, W9t_lo);

    k_attn_mfma<<<dim3(48), 256, 0, stream>>>(X, spans, AW1t_hi, AW1t_lo,
                                              AW2t_hi, AW2t_lo, ab1, ab2, aw3, ab3, attn_g);
    k_span_g<<<dim3(BB * SS), 256, 0, stream>>>(X, spans, attn_g, G_ws, Gs_hi, Gs_lo);
    k_uvm<<<dim3(3, 3, 4), 256, 0, stream>>>(Gs_hi, Gs_lo, W9t_hi, W9t_lo, UVM);
    k_mention<<<dim3(BB * SS), 256, 0, stream>>>(M_ws, mb1, mw2, mb2, mw3, mb3, m_ws);
    k_pairmm<<<dim3(3, SS, BB), 256, 0, stream>>>(G_ws, PCt_hi, PCt_lo, H1parts);

    const long H1sz = (long)BB * SS * SS * 160;
    k_pair2<<<dim3(BB * SS), 256, 0, stream>>>(
        H1parts, H1parts + H1sz, H1parts + 2 * H1sz,
        U_ws, V_ws, pb1, m_ws, PW2t_hi, PW2t_lo, pb2, pw3, pb3, out);
}

// Round 5
// 268.882 us; speedup vs baseline: 3.6171x; 1.0797x over previous
//
#include <hip/hip_runtime.h>

// Problem constants
#define EDIM   768
#define E3     2304
#define HIDD   150
#define TT     2048
#define SS     96
#define BB     2

typedef unsigned short u16;
using frag   = __attribute__((ext_vector_type(8))) short;   // 8 bf16 = 4 VGPR
using f32x4v = __attribute__((ext_vector_type(4))) float;   // 4 fp32 acc
using u16x8  = __attribute__((ext_vector_type(8))) unsigned short;

__device__ __forceinline__ u16 bf16rn(float f) {
    union { float f; unsigned u; } v; v.f = f;
    unsigned r = v.u + 0x7FFF + ((v.u >> 16) & 1);
    return (u16)(r >> 16);
}
__device__ __forceinline__ float bf16tof(u16 h) {
    union { unsigned u; float f; } v; v.u = ((unsigned)h) << 16;
    return v.f;
}
__device__ __forceinline__ void split2(float f, u16& hi, u16& lo) {
    hi = bf16rn(f); lo = bf16rn(f - bf16tof(hi));
}

// ---------------------------------------------------------------------------
// k_prep_w12: W12t[n][k] bf16 hi/lo, n in [0,640): rows 0-159 = PA cols,
// 160-319 = PB cols, 320-479 = mw1 cols, 480-639 = PC cols (pairmm B).
// Tiled transpose: grid (36 k-tiles of 64, 20 n-tiles of 32), 256 thr.
// ---------------------------------------------------------------------------
__global__ __launch_bounds__(256) void k_prep_w12(
    const float* __restrict__ pw1, const float* __restrict__ mw1,
    u16* __restrict__ W_hi, u16* __restrict__ W_lo)
{
    __shared__ float tile[64][33];
    const int t  = threadIdx.x;
    const int k0 = blockIdx.x * 64;
    const int n0 = blockIdx.y * 32;
    const int seg = n0 / 160;             // tile never straddles (160%32==0)
    const int nloc0 = n0 - seg * 160;

    for (int idx = t; idx < 2048; idx += 256) {
        const int kk = idx >> 5, nn = idx & 31;
        const int nl = nloc0 + nn;
        const int k  = k0 + kk;
        float v = 0.f;
        if (nl < HIDD) {
            if (seg == 0)      v = pw1[(long)k * HIDD + nl];
            else if (seg == 1) v = pw1[(long)(E3 + k) * HIDD + nl];
            else if (seg == 2) v = mw1[(long)k * HIDD + nl];
            else               v = pw1[(long)(2 * E3 + k) * HIDD + nl];
        }
        tile[kk][nn] = v;
    }
    __syncthreads();
    for (int idx = t; idx < 2048; idx += 256) {
        const int nn = idx >> 6, kk = idx & 63;
        u16 hi, lo; split2(tile[kk][nn], hi, lo);
        W_hi[(long)(n0 + nn) * E3 + k0 + kk] = hi;
        W_lo[(long)(n0 + nn) * E3 + k0 + kk] = lo;
    }
}

// AW1t[n][k], n in [0,160), k in [0,768)
__global__ __launch_bounds__(256) void k_prep_aw1(
    const float* __restrict__ aw1, u16* __restrict__ W_hi, u16* __restrict__ W_lo)
{
    const int k = blockIdx.x, t = threadIdx.x;
    if (t < 160) {
        float v = (t < HIDD) ? aw1[k * HIDD + t] : 0.f;
        u16 hi, lo; split2(v, hi, lo);
        W_hi[(long)t * EDIM + k] = hi;
        W_lo[(long)t * EDIM + k] = lo;
    }
}
// k_prep_sq: AW2t (y=0) and PW2t (y=1), 160x160 transposed split.
__global__ __launch_bounds__(256) void k_prep_sq(
    const float* __restrict__ aw2, const float* __restrict__ pw2,
    u16* __restrict__ A_hi, u16* __restrict__ A_lo,
    u16* __restrict__ P_hi, u16* __restrict__ P_lo)
{
    const int k = blockIdx.x, t = threadIdx.x;
    const float* src = blockIdx.y ? pw2 : aw2;
    u16* dh = blockIdx.y ? P_hi : A_hi;
    u16* dl = blockIdx.y ? P_lo : A_lo;
    if (t < 160) {
        float v = (t < HIDD && k < HIDD) ? src[k * HIDD + t] : 0.f;
        u16 hi, lo; split2(v, hi, lo);
        dh[t * 160 + k] = hi;
        dl[t * 160 + k] = lo;
    }
}

// ---------------------------------------------------------------------------
// k_attn_mfma: attn scores ONLY at span-gathered positions (1536 rows).
// ---------------------------------------------------------------------------
__global__ __launch_bounds__(256) void k_attn_mfma(
    const float* __restrict__ X, const int* __restrict__ spans,
    const u16* __restrict__ AW1t_hi, const u16* __restrict__ AW1t_lo,
    const u16* __restrict__ AW2t_hi, const u16* __restrict__ AW2t_lo,
    const float* __restrict__ ab1, const float* __restrict__ ab2,
    const float* __restrict__ aw3, const float* __restrict__ ab3,
    float* __restrict__ attn_g)
{
    __shared__ __align__(16) u16 As_hi[32 * 40];
    __shared__ __align__(16) u16 As_lo[32 * 40];
    __shared__ __align__(16) u16 Bs_hi[160 * 40];
    __shared__ __align__(16) u16 Bs_lo[160 * 40];
    __shared__ float h1s[32 * 160];
    __shared__ float red[32];

    const int t    = threadIdx.x;
    const int lane = t & 63;
    const int m    = lane & 15;
    const int quad = lane >> 4;
    const int w    = t >> 6;
    const int mt   = (w & 1) * 16;
    const int nb   = (w >> 1) * 80;

    const int rr = t >> 3, q = t & 7;
    const int grow = blockIdx.x * 32 + rr;
    const int bs = grow >> 3, sw = grow & 7;
    const int b  = bs / SS;
    const int tok = spans[bs] + sw;
    const float* arow = X + ((long)b * TT + tok) * EDIM;

    f32x4v acc[5];
    #pragma unroll
    for (int ht = 0; ht < 5; ++ht)
        #pragma unroll
        for (int r = 0; r < 4; ++r) acc[ht][r] = 0.f;

    for (int tt = 0; tt < 24; ++tt) {
        const int kk0 = tt * 32;
        {
            const float4 xv = *(const float4*)&arow[kk0 + q * 4];
            ushort4 hv, lv;
            split2(xv.x, hv.x, lv.x); split2(xv.y, hv.y, lv.y);
            split2(xv.z, hv.z, lv.z); split2(xv.w, hv.w, lv.w);
            *(ushort4*)&As_hi[rr * 40 + q * 4] = hv;
            *(ushort4*)&As_lo[rr * 40 + q * 4] = lv;
        }
        #pragma unroll
        for (int it = 0; it < 3; ++it) {
            const int v = t + it * 256;
            if (v < 640) {
                const int h = v >> 2, qq = v & 3;
                *(uint4*)&Bs_hi[h * 40 + qq * 8] = *(const uint4*)&AW1t_hi[(long)h * EDIM + kk0 + qq * 8];
                *(uint4*)&Bs_lo[h * 40 + qq * 8] = *(const uint4*)&AW1t_lo[(long)h * EDIM + kk0 + qq * 8];
            }
        }
        __syncthreads();
        const frag ah = *(const frag*)&As_hi[(mt + m) * 40 + quad * 8];
        const frag al = *(const frag*)&As_lo[(mt + m) * 40 + quad * 8];
        #pragma unroll
        for (int ht = 0; ht < 5; ++ht) {
            const frag bh = *(const frag*)&Bs_hi[(nb + ht * 16 + m) * 40 + quad * 8];
            const frag bl = *(const frag*)&Bs_lo[(nb + ht * 16 + m) * 40 + quad * 8];
            acc[ht] = __builtin_amdgcn_mfma_f32_16x16x32_bf16(al, bh, acc[ht], 0, 0, 0);
            acc[ht] = __builtin_amdgcn_mfma_f32_16x16x32_bf16(ah, bl, acc[ht], 0, 0, 0);
            acc[ht] = __builtin_amdgcn_mfma_f32_16x16x32_bf16(ah, bh, acc[ht], 0, 0, 0);
        }
        __syncthreads();
    }
    #pragma unroll
    for (int ht = 0; ht < 5; ++ht) {
        #pragma unroll
        for (int r = 0; r < 4; ++r) {
            const int row = mt + quad * 4 + r;
            const int col = nb + ht * 16 + m;
            const float v = (col < HIDD) ? fmaxf(acc[ht][r] + ab1[col], 0.f) : 0.f;
            h1s[row * 160 + col] = v;
        }
    }
    __syncthreads();

    f32x4v acc2[5];
    #pragma unroll
    for (int ht = 0; ht < 5; ++ht)
        #pragma unroll
        for (int r = 0; r < 4; ++r) acc2[ht][r] = 0.f;

    for (int kk = 0; kk < 5; ++kk) {
        {
            const float4 xv = *(const float4*)&h1s[rr * 160 + kk * 32 + q * 4];
            ushort4 hv, lv;
            split2(xv.x, hv.x, lv.x); split2(xv.y, hv.y, lv.y);
            split2(xv.z, hv.z, lv.z); split2(xv.w, hv.w, lv.w);
            *(ushort4*)&As_hi[rr * 40 + q * 4] = hv;
            *(ushort4*)&As_lo[rr * 40 + q * 4] = lv;
        }
        #pragma unroll
        for (int it = 0; it < 3; ++it) {
            const int v = t + it * 256;
            if (v < 640) {
                const int h = v >> 2, qq = v & 3;
                *(uint4*)&Bs_hi[h * 40 + qq * 8] = *(const uint4*)&AW2t_hi[h * 160 + kk * 32 + qq * 8];
                *(uint4*)&Bs_lo[h * 40 + qq * 8] = *(const uint4*)&AW2t_lo[h * 160 + kk * 32 + qq * 8];
            }
        }
        __syncthreads();
        const frag ah = *(const frag*)&As_hi[(mt + m) * 40 + quad * 8];
        const frag al = *(const frag*)&As_lo[(mt + m) * 40 + quad * 8];
        #pragma unroll
        for (int ht = 0; ht < 5; ++ht) {
            const frag bh = *(const frag*)&Bs_hi[(nb + ht * 16 + m) * 40 + quad * 8];
            const frag bl = *(const frag*)&Bs_lo[(nb + ht * 16 + m) * 40 + quad * 8];
            acc2[ht] = __builtin_amdgcn_mfma_f32_16x16x32_bf16(al, bh, acc2[ht], 0, 0, 0);
            acc2[ht] = __builtin_amdgcn_mfma_f32_16x16x32_bf16(ah, bl, acc2[ht], 0, 0, 0);
            acc2[ht] = __builtin_amdgcn_mfma_f32_16x16x32_bf16(ah, bh, acc2[ht], 0, 0, 0);
        }
        __syncthreads();
    }

    if (t < 32) red[t] = 0.f;
    __syncthreads();
    float s[4] = {0.f, 0.f, 0.f, 0.f};
    #pragma unroll
    for (int ht = 0; ht < 5; ++ht) {
        const int col = nb + ht * 16 + m;
        if (col < HIDD) {
            const float w3 = aw3[col];
            #pragma unroll
            for (int r = 0; r < 4; ++r)
                s[r] += fmaxf(acc2[ht][r] + ab2[col], 0.f) * w3;
        }
    }
    #pragma unroll
    for (int r = 0; r < 4; ++r) {
        for (int off = 8; off > 0; off >>= 1) s[r] += __shfl_down(s[r], off, 16);
    }
    if (m == 0) {
        #pragma unroll
        for (int r = 0; r < 4; ++r) atomicAdd(&red[mt + quad * 4 + r], s[r]);
    }
    __syncthreads();
    if (t < 32) attn_g[blockIdx.x * 32 + t] = red[t] + ab3[0];
}

// ---------------------------------------------------------------------------
// k_span_g: build g_i fp32 (G_ws) AND bf16 hi/lo split (Gs_hi/lo). 192 blocks.
// ---------------------------------------------------------------------------
__global__ __launch_bounds__(256) void k_span_g(
    const float* __restrict__ X, const int* __restrict__ spans,
    const float* __restrict__ attn_g, float* __restrict__ G_ws,
    u16* __restrict__ Gs_hi, u16* __restrict__ Gs_lo)
{
    __shared__ float a8[8];
    const int t  = threadIdx.x;
    const int bs = blockIdx.x;
    const int b  = bs / SS;
    const int start = spans[bs];
    const float* xb = X + ((long)b * TT + start) * EDIM;
    float* Gp = G_ws + (long)bs * E3;
    u16* Gh = Gs_hi + (long)bs * E3;
    u16* Gl = Gs_lo + (long)bs * E3;
    if (t < 8) a8[t] = attn_g[bs * 8 + t];
    __syncthreads();

    for (int e = t; e < EDIM; e += 256) {
        const float gs = xb[e];
        const float ge = xb[7 * EDIM + e];
        float ga = 0.f;
        #pragma unroll
        for (int w = 0; w < 8; ++w) ga += xb[w * EDIM + e] * a8[w];
        Gp[e] = gs; Gp[EDIM + e] = ge; Gp[2 * EDIM + e] = ga;
        u16 hi, lo;
        split2(gs, hi, lo); Gh[e] = hi;            Gl[e] = lo;
        split2(ge, hi, lo); Gh[EDIM + e] = hi;     Gl[EDIM + e] = lo;
        split2(ga, hi, lo); Gh[2 * EDIM + e] = hi; Gl[2 * EDIM + e] = lo;
    }
}

// ---------------------------------------------------------------------------
// k_uvm: MFMA GEMM [192x2304] @ W12t(rows 0..480)^T -> UVM[3][192][160].
// ---------------------------------------------------------------------------
__global__ __launch_bounds__(256) void k_uvm(
    const u16* __restrict__ Gs_hi, const u16* __restrict__ Gs_lo,
    const u16* __restrict__ W9t_hi, const u16* __restrict__ W9t_lo,
    float* __restrict__ UVM)
{
    __shared__ __align__(16) u16 As_hi[64 * 40];
    __shared__ __align__(16) u16 As_lo[64 * 40];
    __shared__ __align__(16) u16 Bs_hi[160 * 40];
    __shared__ __align__(16) u16 Bs_lo[160 * 40];

    const int t    = threadIdx.x;
    const int mb   = blockIdx.x;
    const int nb   = blockIdx.y;
    const int ks   = blockIdx.z;
    const int lane = t & 63;
    const int m    = lane & 15;
    const int quad = lane >> 4;
    const int w    = t >> 6;
    const int mhalf = (w & 1) * 32;
    const int nbase = (w >> 1) * 80;
    const int arr = t >> 2, aq = t & 3;

    f32x4v acc[2][5];
    #pragma unroll
    for (int i = 0; i < 2; ++i)
        #pragma unroll
        for (int j = 0; j < 5; ++j)
            #pragma unroll
            for (int r = 0; r < 4; ++r) acc[i][j][r] = 0.f;

    for (int tt = 0; tt < 18; ++tt) {
        const int kk0 = ks * 576 + tt * 32;
        *(uint4*)&As_hi[arr * 40 + aq * 8] = *(const uint4*)&Gs_hi[(long)(mb * 64 + arr) * E3 + kk0 + aq * 8];
        *(uint4*)&As_lo[arr * 40 + aq * 8] = *(const uint4*)&Gs_lo[(long)(mb * 64 + arr) * E3 + kk0 + aq * 8];
        #pragma unroll
        for (int it = 0; it < 3; ++it) {
            const int v = t + it * 256;
            if (v < 640) {
                const int h = v >> 2, qq = v & 3;
                *(uint4*)&Bs_hi[h * 40 + qq * 8] = *(const uint4*)&W9t_hi[(long)(nb * 160 + h) * E3 + kk0 + qq * 8];
                *(uint4*)&Bs_lo[h * 40 + qq * 8] = *(const uint4*)&W9t_lo[(long)(nb * 160 + h) * E3 + kk0 + qq * 8];
            }
        }
        __syncthreads();
        frag ah[2], al[2];
        #pragma unroll
        for (int mt = 0; mt < 2; ++mt) {
            ah[mt] = *(const frag*)&As_hi[(mhalf + mt * 16 + m) * 40 + quad * 8];
            al[mt] = *(const frag*)&As_lo[(mhalf + mt * 16 + m) * 40 + quad * 8];
        }
        #pragma unroll
        for (int ht = 0; ht < 5; ++ht) {
            const frag bh = *(const frag*)&Bs_hi[(nbase + ht * 16 + m) * 40 + quad * 8];
            const frag bl = *(const frag*)&Bs_lo[(nbase + ht * 16 + m) * 40 + quad * 8];
            #pragma unroll
            for (int mt = 0; mt < 2; ++mt) {
                acc[mt][ht] = __builtin_amdgcn_mfma_f32_16x16x32_bf16(al[mt], bh, acc[mt][ht], 0, 0, 0);
                acc[mt][ht] = __builtin_amdgcn_mfma_f32_16x16x32_bf16(ah[mt], bl, acc[mt][ht], 0, 0, 0);
                acc[mt][ht] = __builtin_amdgcn_mfma_f32_16x16x32_bf16(ah[mt], bh, acc[mt][ht], 0, 0, 0);
            }
        }
        __syncthreads();
    }
    float* dst = UVM + (long)nb * (192 * 160);
    #pragma unroll
    for (int mt = 0; mt < 2; ++mt) {
        #pragma unroll
        for (int ht = 0; ht < 5; ++ht) {
            #pragma unroll
            for (int r = 0; r < 4; ++r) {
                const int row = mb * 64 + mhalf + mt * 16 + quad * 4 + r;
                const int c   = nbase + ht * 16 + m;
                atomicAdd(&dst[row * 160 + c], acc[mt][ht][r]);
            }
        }
    }
}

// ---------------------------------------------------------------------------
// k_mention: mention MLP layers 2-3 from M partials (stride 160). 192 blocks.
// ---------------------------------------------------------------------------
__global__ __launch_bounds__(256) void k_mention(
    const float* __restrict__ M_ws,
    const float* __restrict__ mb1,
    const float* __restrict__ mw2, const float* __restrict__ mb2,
    const float* __restrict__ mw3, const float* __restrict__ mb3,
    float* __restrict__ m_ws)
{
    __shared__ float h1m[152];
    __shared__ float h2m[152];
    __shared__ float red[256];
    const int t  = threadIdx.x;
    const int bs = blockIdx.x;
    if (t < HIDD) h1m[t] = fmaxf(M_ws[bs * 160 + t] + mb1[t], 0.f);
    __syncthreads();
    if (t < HIDD) {
        float a = mb2[t];
        for (int k = 0; k < HIDD; ++k) a += h1m[k] * mw2[k * HIDD + t];
        h2m[t] = fmaxf(a, 0.f);
    }
    __syncthreads();
    red[t] = (t < HIDD) ? h2m[t] * mw3[t] : 0.f;
    __syncthreads();
    for (int off = 128; off > 0; off >>= 1) {
        if (t < off) red[t] += red[t + off];
        __syncthreads();
    }
    if (t == 0) m_ws[bs] = red[0] + mb3[0];
}

// ---------------------------------------------------------------------------
// k_pairmm: MFMA bilinear, SYMMETRIC (only j-tiles >= i-tile; C[i,j]=C[j,i]).
// LDS tiles are unpadded 64B-row [rel_row][32k] -> conflict-free b128 r/w.
// Wave w: h-half = (w&1)*80; j-tiles a = (w>>1) + 2u (a < ntiles).
// Output row (b*96+i)*96 + j stride 160; pair2 reads [min*96+max].
// ---------------------------------------------------------------------------
__global__ __launch_bounds__(256) void k_pairmm(
    const float* __restrict__ G_ws,
    const u16* __restrict__ PCt_hi, const u16* __restrict__ PCt_lo,
    float* __restrict__ H1parts)
{
    __shared__ float gis[768];
    __shared__ __align__(16) u16 As_hi[96 * 32];
    __shared__ __align__(16) u16 As_lo[96 * 32];
    __shared__ __align__(16) u16 Bs_hi[160 * 32];
    __shared__ __align__(16) u16 Bs_lo[160 * 32];

    const int t  = threadIdx.x;
    const int ks = blockIdx.x;
    const int i  = blockIdx.y;
    const int b  = blockIdx.z;
    const int ksbase = ks * 768;
    const int jt0 = i >> 4;
    const int ntiles = 6 - jt0;
    const int j0 = jt0 * 16;
    const int R  = 96 - j0;

    const int lane = t & 63;
    const int m    = lane & 15;
    const int quad = lane >> 4;
    const int w    = t >> 6;
    const int hb   = (w & 1) * 80;
    const int apar = w >> 1;

    const float* Gi = G_ws + (long)(b * SS + i) * E3 + ksbase;
    for (int e = t; e < 768; e += 256) gis[e] = Gi[e];
    __syncthreads();

    f32x4v acc[3][5];
    #pragma unroll
    for (int jt = 0; jt < 3; ++jt)
        #pragma unroll
        for (int ht = 0; ht < 5; ++ht)
            #pragma unroll
            for (int r = 0; r < 4; ++r) acc[jt][ht][r] = 0.f;

    for (int tt = 0; tt < 24; ++tt) {
        const int kk0 = ksbase + tt * 32;
        // A: products gi*gj for rows [j0,96), 8 per thread, 16B LDS writes
        for (int u = t; u < R * 4; u += 256) {
            const int rr = u >> 2;
            const int qd = u & 3;
            const float* gj = &G_ws[(long)(b * SS + j0 + rr) * E3 + kk0 + qd * 8];
            const float4 g0 = *(const float4*)&gj[0];
            const float4 g1 = *(const float4*)&gj[4];
            const int kl = tt * 32 + qd * 8;
            u16x8 hv, lv; u16 h, l;
            split2(g0.x * gis[kl + 0], h, l); hv[0] = h; lv[0] = l;
            split2(g0.y * gis[kl + 1], h, l); hv[1] = h; lv[1] = l;
            split2(g0.z * gis[kl + 2], h, l); hv[2] = h; lv[2] = l;
            split2(g0.w * gis[kl + 3], h, l); hv[3] = h; lv[3] = l;
            split2(g1.x * gis[kl + 4], h, l); hv[4] = h; lv[4] = l;
            split2(g1.y * gis[kl + 5], h, l); hv[5] = h; lv[5] = l;
            split2(g1.z * gis[kl + 6], h, l); hv[6] = h; lv[6] = l;
            split2(g1.w * gis[kl + 7], h, l); hv[7] = h; lv[7] = l;
            *(u16x8*)&As_hi[rr * 32 + qd * 8] = hv;
            *(u16x8*)&As_lo[rr * 32 + qd * 8] = lv;
        }
        // B: PCt slice 160x32, row-major 64B rows
        for (int v = t; v < 640; v += 256) {
            const int h = v >> 2, qd = v & 3;
            *(uint4*)&Bs_hi[h * 32 + qd * 8] = *(const uint4*)&PCt_hi[(long)h * E3 + kk0 + qd * 8];
            *(uint4*)&Bs_lo[h * 32 + qd * 8] = *(const uint4*)&PCt_lo[(long)h * E3 + kk0 + qd * 8];
        }
        __syncthreads();
        frag ah[3], al[3];
        #pragma unroll
        for (int u = 0; u < 3; ++u) {
            const int a = apar + 2 * u;
            if (a < ntiles) {
                ah[u] = *(const frag*)&As_hi[(a * 16 + m) * 32 + quad * 8];
                al[u] = *(const frag*)&As_lo[(a * 16 + m) * 32 + quad * 8];
            }
        }
        #pragma unroll
        for (int ht = 0; ht < 5; ++ht) {
            const frag bh = *(const frag*)&Bs_hi[(hb + ht * 16 + m) * 32 + quad * 8];
            const frag bl = *(const frag*)&Bs_lo[(hb + ht * 16 + m) * 32 + quad * 8];
            #pragma unroll
            for (int u = 0; u < 3; ++u) {
                if (apar + 2 * u < ntiles) {
                    acc[u][ht] = __builtin_amdgcn_mfma_f32_16x16x32_bf16(al[u], bh, acc[u][ht], 0, 0, 0);
                    acc[u][ht] = __builtin_amdgcn_mfma_f32_16x16x32_bf16(ah[u], bl, acc[u][ht], 0, 0, 0);
                    acc[u][ht] = __builtin_amdgcn_mfma_f32_16x16x32_bf16(ah[u], bh, acc[u][ht], 0, 0, 0);
                }
            }
        }
        __syncthreads();
    }

    float* dst = H1parts + (long)ks * ((long)BB * SS * SS * 160);
    #pragma unroll
    for (int u = 0; u < 3; ++u) {
        const int a = apar + 2 * u;
        if (a < ntiles) {
            #pragma unroll
            for (int ht = 0; ht < 5; ++ht) {
                #pragma unroll
                for (int r = 0; r < 4; ++r) {
                    const int j = (jt0 + a) * 16 + quad * 4 + r;
                    const int h = hb + ht * 16 + m;
                    dst[((long)(b * SS + i) * SS + j) * 160 + h] = acc[u][ht][r];
                }
            }
        }
    }
}

// ---------------------------------------------------------------------------
// k_pair2: MFMA finish; reads symmetric H1 at [min(i,j)*96+max(i,j)].
// ---------------------------------------------------------------------------
__global__ __launch_bounds__(256) void k_pair2(
    const float* __restrict__ H1a, const float* __restrict__ H1b,
    const float* __restrict__ H1c,
    const float* __restrict__ U_ws, const float* __restrict__ V_ws,
    const float* __restrict__ pb1, const float* __restrict__ m_ws,
    const u16* __restrict__ PW2t_hi, const u16* __restrict__ PW2t_lo,
    const float* __restrict__ pb2, const float* __restrict__ pw3,
    const float* __restrict__ pb3,
    float* __restrict__ out)
{
    __shared__ __align__(16) u16 As_hi[96 * 168];
    __shared__ __align__(16) u16 As_lo[96 * 168];
    __shared__ __align__(16) u16 Bs_hi[160 * 40];
    __shared__ __align__(16) u16 Bs_lo[160 * 40];
    __shared__ float uv[160];
    __shared__ float red[96];

    const int t  = threadIdx.x;
    const int bi = blockIdx.x;          // b*96 + i
    const int b  = bi / SS;
    const int ii = bi - b * SS;

    if (t < 160) uv[t] = U_ws[bi * 160 + t] + ((t < HIDD) ? pb1[t] : 0.f);
    if (t < 96) red[t] = 0.f;
    __syncthreads();

    // phase 1: build split h1 in LDS (symmetric-ordered reads)
    for (int u = t; u < 96 * 40; u += 256) {
        const int j = u / 40, hq = u - (u / 40) * 40;
        const int h0 = hq * 4;
        const int mn = ii < j ? ii : j;
        const int mx = ii < j ? j : ii;
        const long idx = (((long)b * SS + mn) * SS + mx) * 160 + h0;
        const float4 a  = *(const float4*)&H1a[idx];
        const float4 bb = *(const float4*)&H1b[idx];
        const float4 c  = *(const float4*)&H1c[idx];
        const float4 vv = *(const float4*)&V_ws[(b * SS + j) * 160 + h0];
        const float p0 = fmaxf(a.x + bb.x + c.x + vv.x + uv[h0 + 0], 0.f);
        const float p1 = fmaxf(a.y + bb.y + c.y + vv.y + uv[h0 + 1], 0.f);
        const float p2 = fmaxf(a.z + bb.z + c.z + vv.z + uv[h0 + 2], 0.f);
        const float p3 = fmaxf(a.w + bb.w + c.w + vv.w + uv[h0 + 3], 0.f);
        ushort4 hv, lv;
        split2(p0, hv.x, lv.x); split2(p1, hv.y, lv.y);
        split2(p2, hv.z, lv.z); split2(p3, hv.w, lv.w);
        *(ushort4*)&As_hi[j * 168 + h0] = hv;
        *(ushort4*)&As_lo[j * 168 + h0] = lv;
    }
    __syncthreads();

    // phase 2: layer2 MFMA [96x160]@[160x160]
    const int lane = t & 63;
    const int m    = lane & 15;
    const int quad = lane >> 4;
    const int w    = t >> 6;
    const int jbs  = (w & 1) * 48;
    const int nbs  = (w >> 1) * 80;

    f32x4v acc[3][5];
    #pragma unroll
    for (int jt = 0; jt < 3; ++jt)
        #pragma unroll
        for (int ht = 0; ht < 5; ++ht)
            #pragma unroll
            for (int r = 0; r < 4; ++r) acc[jt][ht][r] = 0.f;

    for (int kk = 0; kk < 5; ++kk) {
        #pragma unroll
        for (int it = 0; it < 3; ++it) {
            const int v = t + it * 256;
            if (v < 640) {
                const int n = v >> 2, qq = v & 3;
                *(uint4*)&Bs_hi[n * 40 + qq * 8] = *(const uint4*)&PW2t_hi[n * 160 + kk * 32 + qq * 8];
                *(uint4*)&Bs_lo[n * 40 + qq * 8] = *(const uint4*)&PW2t_lo[n * 160 + kk * 32 + qq * 8];
            }
        }
        __syncthreads();
        frag ah[3], al[3];
        #pragma unroll
        for (int jt = 0; jt < 3; ++jt) {
            ah[jt] = *(const frag*)&As_hi[(jbs + jt * 16 + m) * 168 + kk * 32 + quad * 8];
            al[jt] = *(const frag*)&As_lo[(jbs + jt * 16 + m) * 168 + kk * 32 + quad * 8];
        }
        #pragma unroll
        for (int ht = 0; ht < 5; ++ht) {
            const frag bh = *(const frag*)&Bs_hi[(nbs + ht * 16 + m) * 40 + quad * 8];
            const frag bl = *(const frag*)&Bs_lo[(nbs + ht * 16 + m) * 40 + quad * 8];
            #pragma unroll
            for (int jt = 0; jt < 3; ++jt) {
                acc[jt][ht] = __builtin_amdgcn_mfma_f32_16x16x32_bf16(al[jt], bh, acc[jt][ht], 0, 0, 0);
                acc[jt][ht] = __builtin_amdgcn_mfma_f32_16x16x32_bf16(ah[jt], bl, acc[jt][ht], 0, 0, 0);
                acc[jt][ht] = __builtin_amdgcn_mfma_f32_16x16x32_bf16(ah[jt], bh, acc[jt][ht], 0, 0, 0);
            }
        }
        __syncthreads();
    }

    // phase 3: layer3 dot + reduce
    float s[3][4];
    #pragma unroll
    for (int jt = 0; jt < 3; ++jt)
        #pragma unroll
        for (int r = 0; r < 4; ++r) s[jt][r] = 0.f;
    #pragma unroll
    for (int ht = 0; ht < 5; ++ht) {
        const int col = nbs + ht * 16 + m;
        if (col < HIDD) {
            const float w3 = pw3[col];
            const float b2 = pb2[col];
            #pragma unroll
            for (int jt = 0; jt < 3; ++jt)
                #pragma unroll
                for (int r = 0; r < 4; ++r)
                    s[jt][r] += fmaxf(acc[jt][ht][r] + b2, 0.f) * w3;
        }
    }
    #pragma unroll
    for (int jt = 0; jt < 3; ++jt)
        #pragma unroll
        for (int r = 0; r < 4; ++r)
            for (int off = 8; off > 0; off >>= 1)
                s[jt][r] += __shfl_down(s[jt][r], off, 16);
    if (m == 0) {
        #pragma unroll
        for (int jt = 0; jt < 3; ++jt)
            #pragma unroll
            for (int r = 0; r < 4; ++r)
                atomicAdd(&red[jbs + jt * 16 + quad * 4 + r], s[jt][r]);
    }
    __syncthreads();

    if (t < 96) {
        const float sc = red[t] + pb3[0];
        const float v = (m_ws[bi] + m_ws[b * SS + t] + sc) * (1.f / 3.f);
        out[(long)bi * SS + t] = fminf(fmaxf(v, 0.f), 1.f);
    }
}

// ---------------------------------------------------------------------------
extern "C" void kernel_launch(void* const* d_in, const int* in_sizes, int n_in,
                              void* d_out, int out_size, void* d_ws, size_t ws_size,
                              hipStream_t stream)
{
    const float* X     = (const float*)d_in[0];
    const int*   spans = (const int*)  d_in[1];
    const float* aw1 = (const float*)d_in[2];
    const float* ab1 = (const float*)d_in[3];
    const float* aw2 = (const float*)d_in[4];
    const float* ab2 = (const float*)d_in[5];
    const float* aw3 = (const float*)d_in[6];
    const float* ab3 = (const float*)d_in[7];
    const float* mw1 = (const float*)d_in[8];
    const float* mb1 = (const float*)d_in[9];
    const float* mw2 = (const float*)d_in[10];
    const float* mb2 = (const float*)d_in[11];
    const float* mw3 = (const float*)d_in[12];
    const float* mb3 = (const float*)d_in[13];
    const float* pw1 = (const float*)d_in[14];
    const float* pb1 = (const float*)d_in[15];
    const float* pw2 = (const float*)d_in[16];
    const float* pb2 = (const float*)d_in[17];
    const float* pw3 = (const float*)d_in[18];
    const float* pb3 = (const float*)d_in[19];
    float* out = (float*)d_out;

    char* p = (char*)d_ws;
    float* attn_g  = (float*)p;  p += 6144;                       // 1536 f
    float* G_ws    = (float*)p;  p += (long)442368 * 4;           // 192x2304 f
    u16*   Gs_hi   = (u16*)p;    p += (long)442368 * 2;
    u16*   Gs_lo   = (u16*)p;    p += (long)442368 * 2;
    float* UVM     = (float*)p;  p += (long)3 * 192 * 160 * 4;    // U|V|M
    float* m_ws    = (float*)p;  p += 1024;
    u16*   W12t_hi = (u16*)p;    p += (long)640 * E3 * 2;         // PA|PB|mw1|PC
    u16*   W12t_lo = (u16*)p;    p += (long)640 * E3 * 2;
    u16*   AW1t_hi = (u16*)p;    p += (long)160 * EDIM * 2;
    u16*   AW1t_lo = (u16*)p;    p += (long)160 * EDIM * 2;
    u16*   AW2t_hi = (u16*)p;    p += 160 * 160 * 2;
    u16*   AW2t_lo = (u16*)p;    p += 160 * 160 * 2;
    u16*   PW2t_hi = (u16*)p;    p += 160 * 160 * 2;
    u16*   PW2t_lo = (u16*)p;    p += 160 * 160 * 2;
    float* H1parts = (float*)p;   // 3 * 192*96*160 f = 35.4 MB

    float* U_ws = UVM;
    float* V_ws = UVM + 192 * 160;
    float* M_ws = UVM + 2 * 192 * 160;
    const u16* PCt_hi = W12t_hi + (long)480 * E3;
    const u16* PCt_lo = W12t_lo + (long)480 * E3;

    hipMemsetAsync(UVM, 0, (size_t)3 * 192 * 160 * sizeof(float), stream);

    k_prep_w12<<<dim3(36, 20), 256, 0, stream>>>(pw1, mw1, W12t_hi, W12t_lo);
    k_prep_aw1<<<dim3(EDIM), 256, 0, stream>>>(aw1, AW1t_hi, AW1t_lo);
    k_prep_sq <<<dim3(160, 2), 256, 0, stream>>>(aw2, pw2, AW2t_hi, AW2t_lo, PW2t_hi, PW2t_lo);

    k_attn_mfma<<<dim3(48), 256, 0, stream>>>(X, spans, AW1t_hi, AW1t_lo,
                                              AW2t_hi, AW2t_lo, ab1, ab2, aw3, ab3, attn_g);
    k_span_g<<<dim3(BB * SS), 256, 0, stream>>>(X, spans, attn_g, G_ws, Gs_hi, Gs_lo);
    k_uvm<<<dim3(3, 3, 4), 256, 0, stream>>>(Gs_hi, Gs_lo, W12t_hi, W12t_lo, UVM);
    k_mention<<<dim3(BB * SS), 256, 0, stream>>>(M_ws, mb1, mw2, mb2, mw3, mb3, m_ws);
    k_pairmm<<<dim3(3, SS, BB), 256, 0, stream>>>(G_ws, PCt_hi, PCt_lo, H1parts);

    const long H1sz = (long)BB * SS * SS * 160;
    k_pair2<<<dim3(BB * SS), 256, 0, stream>>>(
        H1parts, H1parts + H1sz, H1parts + 2 * H1sz,
        U_ws, V_ws, pb1, m_ws, PW2t_hi, PW2t_lo, pb2, pw3, pb3, out);
}